// Round 7
// baseline (1158.383 us; speedup 1.0000x reference)
//
#include <hip/hip_runtime.h>
#include <math.h>

#define EPS_MSG 1e-7f

typedef float v2f __attribute__((ext_vector_type(2)));
typedef float v4f __attribute__((ext_vector_type(4)));

static __device__ inline v2f sp(float a) { v2f r; r.x = a; r.y = a; return r; }

__device__ inline unsigned short f2bf(float f) {
    union { float f; unsigned int i; } u; u.f = f;
    unsigned int b = u.i;
    return (unsigned short)((b + 0x7fffu + ((b >> 16) & 1u)) >> 16);
}

// ---------------------------------------------------------------- CSR build
__global__ void zero2_kernel(int* __restrict__ a, int* __restrict__ b, int n) {
    int i = blockIdx.x * 256 + threadIdx.x;
    if (i < n) { a[i] = 0; b[i] = 0; }
}

__global__ void deg_kernel(const int* __restrict__ ei, int* __restrict__ deg, int E) {
    int e = blockIdx.x * 256 + threadIdx.x;
    if (e < E) atomicAdd(&deg[ei[E + e]], 1);
}

__global__ __launch_bounds__(1024)
void scan1_kernel(const int* __restrict__ deg, int* __restrict__ offs,
                  int* __restrict__ bsum, int n) {
    __shared__ int sh[1024];
    int tid = threadIdx.x;
    int i = blockIdx.x * 1024 + tid;
    int v = (i < n) ? deg[i] : 0;
    sh[tid] = v;
    __syncthreads();
    for (int off = 1; off < 1024; off <<= 1) {
        int t = (tid >= off) ? sh[tid - off] : 0;
        __syncthreads();
        sh[tid] += t;
        __syncthreads();
    }
    if (i < n) offs[i] = sh[tid] - v;
    if (tid == 1023) bsum[blockIdx.x] = sh[tid];
}

__global__ __launch_bounds__(64)
void scan2_kernel(int* __restrict__ bsum, int nb) {
    int lane = threadIdx.x;
    int carry = 0;
    for (int base = 0; base < nb; base += 64) {
        int v = (base + lane < nb) ? bsum[base + lane] : 0;
        int incl = v;
#pragma unroll
        for (int off = 1; off < 64; off <<= 1) {
            int t = __shfl_up(incl, off, 64);
            if (lane >= off) incl += t;
        }
        if (base + lane < nb) bsum[base + lane] = incl - v + carry;
        carry += __shfl(incl, 63, 64);
    }
    if (lane == 0) bsum[nb] = carry;
}

__global__ void scan3_kernel(int* __restrict__ offs, const int* __restrict__ bsum, int n) {
    int i = blockIdx.x * 256 + threadIdx.x;
    if (i < n) offs[i] += bsum[i >> 10];
    else if (i == n) offs[n] = bsum[(n + 1023) >> 10];
}

__global__ void scatter_kernel(const int* __restrict__ ei, const float* __restrict__ edge_attr,
                               const int* __restrict__ offs, int* __restrict__ fill,
                               int* __restrict__ src_perm, float* __restrict__ attr_perm, int E) {
    int e = blockIdx.x * 256 + threadIdx.x;
    if (e >= E) return;
    int s = ei[e];
    int d = ei[E + e];
    int pos = offs[d] + atomicAdd(&fill[d], 1);
    src_perm[pos] = s;
    const float4* a = (const float4*)&edge_attr[(size_t)e * 16];
    float4* b = (float4*)&attr_perm[(size_t)pos * 16];
    b[0] = a[0]; b[1] = a[1]; b[2] = a[2]; b[3] = a[3];
}

// ---------------------------------------------------------------- EA precompute (bf16), CSR order, 16 edges per wave
__global__ __launch_bounds__(256)
void ea_csr_kernel(const float* __restrict__ attr_perm,
                   const float* __restrict__ edge_W, const float* __restrict__ edge_b,
                   unsigned short* __restrict__ eab, int Ecut) {
    int lane = threadIdx.x & 63;
    int wbase = (blockIdx.x * 4 + (threadIdx.x >> 6)) * 16;
    if (wbase >= Ecut) return;
    int c0 = lane * 2;
    v2f wE[16];
#pragma unroll
    for (int k = 0; k < 16; ++k) {
        wE[k].x = edge_W[k * 128 + c0];
        wE[k].y = edge_W[k * 128 + c0 + 1];
    }
    v2f eb; eb.x = edge_b[c0]; eb.y = edge_b[c0 + 1];
    int pend = min(wbase + 16, Ecut);
    for (int p = wbase; p < pend; ++p) {
        float av = attr_perm[(size_t)p * 16 + (lane & 15)];
        v2f ea = eb;
#pragma unroll
        for (int k = 0; k < 16; ++k) {
            float ak = __shfl(av, k, 64);
            ea = __builtin_elementwise_fma(sp(ak), wE[k], ea);
        }
        unsigned int u = ((unsigned int)f2bf(ea.y) << 16) | f2bf(ea.x);
        *(unsigned int*)&eab[(size_t)p * 128 + c0] = u;
    }
}

// ---------------------------------------------------------------- node encoder: X = x @ W(64x128) + b
__global__ __launch_bounds__(256)
void encode_kernel(const float* __restrict__ x, const float* __restrict__ W,
                   const float* __restrict__ b, float* __restrict__ out, int N) {
    __shared__ __align__(16) float Xa[32][64];
    int tid = threadIdx.x;
    int node0 = blockIdx.x * 32;
    {
        int row = tid >> 3;
        int col = (tid & 7) * 8;
        float4 v0 = make_float4(0, 0, 0, 0), v1 = make_float4(0, 0, 0, 0);
        if (node0 + row < N) {
            const float* sp_ = &x[(size_t)(node0 + row) * 64 + col];
            v0 = *(const float4*)sp_;
            v1 = *(const float4*)(sp_ + 4);
        }
        *(float4*)&Xa[row][col] = v0;
        *(float4*)&Xa[row][col + 4] = v1;
    }
    __syncthreads();
    int tx = tid & 31, rg = tid >> 5;
    int c = tx * 4;
    v2f ba = *(const v2f*)&b[c];
    v2f bb = *(const v2f*)&b[c + 2];
    v2f acc[4][2];
#pragma unroll
    for (int i = 0; i < 4; ++i) { acc[i][0] = ba; acc[i][1] = bb; }
    for (int k = 0; k < 64; k += 4) {
        v4f W0 = *(const v4f*)&W[(k + 0) * 128 + c];
        v4f W1r = *(const v4f*)&W[(k + 1) * 128 + c];
        v4f W2r = *(const v4f*)&W[(k + 2) * 128 + c];
        v4f W3r = *(const v4f*)&W[(k + 3) * 128 + c];
#pragma unroll
        for (int i = 0; i < 4; ++i) {
            v4f xv = *(const v4f*)&Xa[rg * 4 + i][k];
            acc[i][0] = __builtin_elementwise_fma(sp(xv.x), W0.xy, acc[i][0]);
            acc[i][1] = __builtin_elementwise_fma(sp(xv.x), W0.zw, acc[i][1]);
            acc[i][0] = __builtin_elementwise_fma(sp(xv.y), W1r.xy, acc[i][0]);
            acc[i][1] = __builtin_elementwise_fma(sp(xv.y), W1r.zw, acc[i][1]);
            acc[i][0] = __builtin_elementwise_fma(sp(xv.z), W2r.xy, acc[i][0]);
            acc[i][1] = __builtin_elementwise_fma(sp(xv.z), W2r.zw, acc[i][1]);
            acc[i][0] = __builtin_elementwise_fma(sp(xv.w), W3r.xy, acc[i][0]);
            acc[i][1] = __builtin_elementwise_fma(sp(xv.w), W3r.zw, acc[i][1]);
        }
    }
#pragma unroll
    for (int i = 0; i < 4; ++i) {
        int row = node0 + rg * 4 + i;
        if (row < N) {
            float4 o = make_float4(acc[i][0].x, acc[i][0].y, acc[i][1].x, acc[i][1].y);
            *(float4*)&out[(size_t)row * 128 + c] = o;
        }
    }
}

// ---------------------------------------------------------------- LN(128) + relu
__global__ __launch_bounds__(256)
void ln_relu_kernel(const float* __restrict__ x, const float* __restrict__ g,
                    const float* __restrict__ b, float* __restrict__ out, int N) {
    int lane = threadIdx.x & 63;
    int node = blockIdx.x * 4 + (threadIdx.x >> 6);
    if (node >= N) return;
    int c0 = lane * 2;
    float2 xv = *(const float2*)&x[(size_t)node * 128 + c0];
    float s = xv.x + xv.y;
    float q = xv.x * xv.x + xv.y * xv.y;
#pragma unroll
    for (int m = 1; m < 64; m <<= 1) { s += __shfl_xor(s, m, 64); q += __shfl_xor(q, m, 64); }
    float mu = s * (1.f / 128.f);
    float var = q * (1.f / 128.f) - mu * mu;
    float rs = rsqrtf(var + 1e-5f);
    float ox = fmaxf((xv.x - mu) * rs * g[c0] + b[c0], 0.f);
    float oy = fmaxf((xv.y - mu) * rs * g[c0 + 1] + b[c0 + 1], 0.f);
    float2 o; o.x = ox; o.y = oy;
    *(float2*)&out[(size_t)node * 128 + c0] = o;
}

// ---------------------------------------------------------------- GENConv aggregation (hybrid)
// CSR positions < Ecut: precomputed bf16 EA (u32 load + unpack).
// Positions >= Ecut: recompute ea from attr (R6 path).
__global__ __launch_bounds__(256, 4)
void conv_kernel(const float* __restrict__ pre, const unsigned short* __restrict__ eab,
                 const float* __restrict__ attr_perm,
                 const int* __restrict__ src_perm, const int* __restrict__ offs,
                 const float* __restrict__ edge_W, const float* __restrict__ edge_b,
                 const float* __restrict__ ts, int layer, int Ecut,
                 float* __restrict__ convout, int N) {
    int lane = threadIdx.x & 63;
    int node = blockIdx.x * 4 + (threadIdx.x >> 6);
    if (node >= N) return;
    int c0 = lane * 2;
    float t = ts[layer];
    int i0 = offs[node], i1 = offs[node + 1];
    v2f xself = *(const v2f*)&pre[(size_t)node * 128 + c0];
    float sx = 0.f, sy = 0.f, wx = 0.f, wy = 0.f;
    int i = i0;
    int iA = min(i1, Ecut);
    // ---- EA path, unroll x2
    for (; i + 1 < iA; i += 2) {
        int iu = __builtin_amdgcn_readfirstlane(i);
        int sa = src_perm[iu];
        int sb = src_perm[iu + 1];
        unsigned int ua = *(const unsigned int*)&eab[(size_t)iu * 128 + c0];
        unsigned int ub = *(const unsigned int*)&eab[((size_t)iu + 1) * 128 + c0];
        v2f xa = *(const v2f*)&pre[(size_t)sa * 128 + c0];
        v2f xb = *(const v2f*)&pre[(size_t)sb * 128 + c0];
        union { unsigned int i; float f; } e0, e1, e2, e3;
        e0.i = ua << 16; e1.i = ua & 0xffff0000u;
        e2.i = ub << 16; e3.i = ub & 0xffff0000u;
        float mgax = fmaxf(xa.x + e0.f, 0.f) + EPS_MSG;
        float mgay = fmaxf(xa.y + e1.f, 0.f) + EPS_MSG;
        float mgbx = fmaxf(xb.x + e2.f, 0.f) + EPS_MSG;
        float mgby = fmaxf(xb.y + e3.f, 0.f) + EPS_MSG;
        float exa = __expf(mgax * t), eya = __expf(mgay * t);
        float exb = __expf(mgbx * t), eyb = __expf(mgby * t);
        sx += exa + exb; sy += eya + eyb;
        wx = fmaf(exa, mgax, wx); wx = fmaf(exb, mgbx, wx);
        wy = fmaf(eya, mgay, wy); wy = fmaf(eyb, mgby, wy);
    }
    if (i < iA) {
        int iu = __builtin_amdgcn_readfirstlane(i);
        int sn = src_perm[iu];
        unsigned int ua = *(const unsigned int*)&eab[(size_t)iu * 128 + c0];
        v2f xv = *(const v2f*)&pre[(size_t)sn * 128 + c0];
        union { unsigned int i; float f; } e0, e1;
        e0.i = ua << 16; e1.i = ua & 0xffff0000u;
        float mgx = fmaxf(xv.x + e0.f, 0.f) + EPS_MSG;
        float mgy = fmaxf(xv.y + e1.f, 0.f) + EPS_MSG;
        float ex = __expf(mgx * t), ey = __expf(mgy * t);
        sx += ex; sy += ey;
        wx = fmaf(ex, mgx, wx);
        wy = fmaf(ey, mgy, wy);
        ++i;
    }
    // ---- recompute path (tail beyond Ecut)
    if (i < i1) {
        v2f wE[16];
#pragma unroll
        for (int k = 0; k < 16; ++k) {
            wE[k].x = edge_W[k * 128 + c0];
            wE[k].y = edge_W[k * 128 + c0 + 1];
        }
        v2f eb; eb.x = edge_b[c0]; eb.y = edge_b[c0 + 1];
        for (; i + 1 < i1; i += 2) {
            int iu = __builtin_amdgcn_readfirstlane(i);
            int sa = src_perm[iu];
            int sb = src_perm[iu + 1];
            const v4f* ar = (const v4f*)(attr_perm + (size_t)iu * 16);
            v4f A0 = ar[0], A1 = ar[1], A2 = ar[2], A3 = ar[3];
            v4f B0 = ar[4], B1 = ar[5], B2 = ar[6], B3 = ar[7];
            v2f xa = *(const v2f*)&pre[(size_t)sa * 128 + c0];
            v2f xb = *(const v2f*)&pre[(size_t)sb * 128 + c0];
            v2f ea = eb, eb2 = eb;
            ea  = __builtin_elementwise_fma(sp(A0.x), wE[0], ea);
            eb2 = __builtin_elementwise_fma(sp(B0.x), wE[0], eb2);
            ea  = __builtin_elementwise_fma(sp(A0.y), wE[1], ea);
            eb2 = __builtin_elementwise_fma(sp(B0.y), wE[1], eb2);
            ea  = __builtin_elementwise_fma(sp(A0.z), wE[2], ea);
            eb2 = __builtin_elementwise_fma(sp(B0.z), wE[2], eb2);
            ea  = __builtin_elementwise_fma(sp(A0.w), wE[3], ea);
            eb2 = __builtin_elementwise_fma(sp(B0.w), wE[3], eb2);
            ea  = __builtin_elementwise_fma(sp(A1.x), wE[4], ea);
            eb2 = __builtin_elementwise_fma(sp(B1.x), wE[4], eb2);
            ea  = __builtin_elementwise_fma(sp(A1.y), wE[5], ea);
            eb2 = __builtin_elementwise_fma(sp(B1.y), wE[5], eb2);
            ea  = __builtin_elementwise_fma(sp(A1.z), wE[6], ea);
            eb2 = __builtin_elementwise_fma(sp(B1.z), wE[6], eb2);
            ea  = __builtin_elementwise_fma(sp(A1.w), wE[7], ea);
            eb2 = __builtin_elementwise_fma(sp(B1.w), wE[7], eb2);
            ea  = __builtin_elementwise_fma(sp(A2.x), wE[8], ea);
            eb2 = __builtin_elementwise_fma(sp(B2.x), wE[8], eb2);
            ea  = __builtin_elementwise_fma(sp(A2.y), wE[9], ea);
            eb2 = __builtin_elementwise_fma(sp(B2.y), wE[9], eb2);
            ea  = __builtin_elementwise_fma(sp(A2.z), wE[10], ea);
            eb2 = __builtin_elementwise_fma(sp(B2.z), wE[10], eb2);
            ea  = __builtin_elementwise_fma(sp(A2.w), wE[11], ea);
            eb2 = __builtin_elementwise_fma(sp(B2.w), wE[11], eb2);
            ea  = __builtin_elementwise_fma(sp(A3.x), wE[12], ea);
            eb2 = __builtin_elementwise_fma(sp(B3.x), wE[12], eb2);
            ea  = __builtin_elementwise_fma(sp(A3.y), wE[13], ea);
            eb2 = __builtin_elementwise_fma(sp(B3.y), wE[13], eb2);
            ea  = __builtin_elementwise_fma(sp(A3.z), wE[14], ea);
            eb2 = __builtin_elementwise_fma(sp(B3.z), wE[14], eb2);
            ea  = __builtin_elementwise_fma(sp(A3.w), wE[15], ea);
            eb2 = __builtin_elementwise_fma(sp(B3.w), wE[15], eb2);
            float mgax = fmaxf(xa.x + ea.x, 0.f) + EPS_MSG;
            float mgay = fmaxf(xa.y + ea.y, 0.f) + EPS_MSG;
            float mgbx = fmaxf(xb.x + eb2.x, 0.f) + EPS_MSG;
            float mgby = fmaxf(xb.y + eb2.y, 0.f) + EPS_MSG;
            float exa = __expf(mgax * t), eya = __expf(mgay * t);
            float exb = __expf(mgbx * t), eyb = __expf(mgby * t);
            sx += exa + exb; sy += eya + eyb;
            wx = fmaf(exa, mgax, wx); wx = fmaf(exb, mgbx, wx);
            wy = fmaf(eya, mgay, wy); wy = fmaf(eyb, mgby, wy);
        }
        if (i < i1) {
            int iu = __builtin_amdgcn_readfirstlane(i);
            int sn = src_perm[iu];
            const v4f* ar = (const v4f*)(attr_perm + (size_t)iu * 16);
            v4f A0 = ar[0], A1 = ar[1], A2 = ar[2], A3 = ar[3];
            v2f xv = *(const v2f*)&pre[(size_t)sn * 128 + c0];
            v2f ea = eb;
            ea = __builtin_elementwise_fma(sp(A0.x), wE[0], ea);
            ea = __builtin_elementwise_fma(sp(A0.y), wE[1], ea);
            ea = __builtin_elementwise_fma(sp(A0.z), wE[2], ea);
            ea = __builtin_elementwise_fma(sp(A0.w), wE[3], ea);
            ea = __builtin_elementwise_fma(sp(A1.x), wE[4], ea);
            ea = __builtin_elementwise_fma(sp(A1.y), wE[5], ea);
            ea = __builtin_elementwise_fma(sp(A1.z), wE[6], ea);
            ea = __builtin_elementwise_fma(sp(A1.w), wE[7], ea);
            ea = __builtin_elementwise_fma(sp(A2.x), wE[8], ea);
            ea = __builtin_elementwise_fma(sp(A2.y), wE[9], ea);
            ea = __builtin_elementwise_fma(sp(A2.z), wE[10], ea);
            ea = __builtin_elementwise_fma(sp(A2.w), wE[11], ea);
            ea = __builtin_elementwise_fma(sp(A3.x), wE[12], ea);
            ea = __builtin_elementwise_fma(sp(A3.y), wE[13], ea);
            ea = __builtin_elementwise_fma(sp(A3.z), wE[14], ea);
            ea = __builtin_elementwise_fma(sp(A3.w), wE[15], ea);
            float mgx = fmaxf(xv.x + ea.x, 0.f) + EPS_MSG;
            float mgy = fmaxf(xv.y + ea.y, 0.f) + EPS_MSG;
            float ex = __expf(mgx * t), ey = __expf(mgy * t);
            sx += ex; sy += ey;
            wx = fmaf(ex, mgx, wx);
            wy = fmaf(ey, mgy, wy);
        }
    }
    float ax = (sx > 0.f) ? wx / sx : 0.f;
    float ay = (sy > 0.f) ? wy / sy : 0.f;
    v2f o; o.x = ax + xself.x; o.y = ay + xself.y;
    *(v2f*)&convout[(size_t)node * 128 + c0] = o;
}

// ---------------------------------------------------------------- fused MLP (R3 version: 32-node tile, LDS-staged)
template <int RES>
__global__ __launch_bounds__(256)
void mlp_kernel(const float* __restrict__ convin, const float* __restrict__ W1,
                const float* __restrict__ b1, const float* __restrict__ g1,
                const float* __restrict__ be1, const float* __restrict__ W2,
                const float* __restrict__ b2, const float* __restrict__ xold,
                float* __restrict__ xnew, int N) {
    __shared__ __align__(16) float Xa[32][128];
    __shared__ __align__(16) float Xh[32][256];
    int tid = threadIdx.x;
    int node0 = blockIdx.x * 32;
    {
        int row = tid >> 3;
        int col = (tid & 7) * 16;
        float4 v0 = make_float4(0, 0, 0, 0), v1 = v0, v2 = v0, v3 = v0;
        if (node0 + row < N) {
            const float4* sp_ = (const float4*)&convin[(size_t)(node0 + row) * 128 + col];
            v0 = sp_[0]; v1 = sp_[1]; v2 = sp_[2]; v3 = sp_[3];
        }
        *(float4*)&Xa[row][col + 0] = v0;
        *(float4*)&Xa[row][col + 4] = v1;
        *(float4*)&Xa[row][col + 8] = v2;
        *(float4*)&Xa[row][col + 12] = v3;
    }
    __syncthreads();
    {
        int tx = tid & 63, ty = tid >> 6;
        int c = tx * 4;
        v2f b1a = *(const v2f*)&b1[c];
        v2f b1b = *(const v2f*)&b1[c + 2];
        v2f acc[8][2];
#pragma unroll
        for (int i = 0; i < 8; ++i) { acc[i][0] = b1a; acc[i][1] = b1b; }
        for (int k = 0; k < 128; k += 4) {
            v4f W0 = *(const v4f*)&W1[(size_t)(k + 0) * 256 + c];
            v4f W1r = *(const v4f*)&W1[(size_t)(k + 1) * 256 + c];
            v4f W2r = *(const v4f*)&W1[(size_t)(k + 2) * 256 + c];
            v4f W3r = *(const v4f*)&W1[(size_t)(k + 3) * 256 + c];
#pragma unroll
            for (int i = 0; i < 8; ++i) {
                v4f xv = *(const v4f*)&Xa[ty * 8 + i][k];
                acc[i][0] = __builtin_elementwise_fma(sp(xv.x), W0.xy, acc[i][0]);
                acc[i][1] = __builtin_elementwise_fma(sp(xv.x), W0.zw, acc[i][1]);
                acc[i][0] = __builtin_elementwise_fma(sp(xv.y), W1r.xy, acc[i][0]);
                acc[i][1] = __builtin_elementwise_fma(sp(xv.y), W1r.zw, acc[i][1]);
                acc[i][0] = __builtin_elementwise_fma(sp(xv.z), W2r.xy, acc[i][0]);
                acc[i][1] = __builtin_elementwise_fma(sp(xv.z), W2r.zw, acc[i][1]);
                acc[i][0] = __builtin_elementwise_fma(sp(xv.w), W3r.xy, acc[i][0]);
                acc[i][1] = __builtin_elementwise_fma(sp(xv.w), W3r.zw, acc[i][1]);
            }
        }
        v2f g1a = *(const v2f*)&g1[c];
        v2f g1b = *(const v2f*)&g1[c + 2];
        v2f bea = *(const v2f*)&be1[c];
        v2f beb = *(const v2f*)&be1[c + 2];
#pragma unroll
        for (int i = 0; i < 8; ++i) {
            float s = acc[i][0].x + acc[i][0].y + acc[i][1].x + acc[i][1].y;
            float q = acc[i][0].x * acc[i][0].x + acc[i][0].y * acc[i][0].y +
                      acc[i][1].x * acc[i][1].x + acc[i][1].y * acc[i][1].y;
#pragma unroll
            for (int m = 1; m < 64; m <<= 1) { s += __shfl_xor(s, m, 64); q += __shfl_xor(q, m, 64); }
            float mu = s * (1.f / 256.f);
            float var = q * (1.f / 256.f) - mu * mu;
            float rs = rsqrtf(var + 1e-5f);
            float h0 = fmaxf((acc[i][0].x - mu) * rs * g1a.x + bea.x, 0.f);
            float h1 = fmaxf((acc[i][0].y - mu) * rs * g1a.y + bea.y, 0.f);
            float h2 = fmaxf((acc[i][1].x - mu) * rs * g1b.x + beb.x, 0.f);
            float h3 = fmaxf((acc[i][1].y - mu) * rs * g1b.y + beb.y, 0.f);
            *(float4*)&Xh[ty * 8 + i][c] = make_float4(h0, h1, h2, h3);
        }
    }
    __syncthreads();
    {
        int tx2 = tid & 31, rg = tid >> 5;
        int c2 = tx2 * 4;
        v2f b2a = *(const v2f*)&b2[c2];
        v2f b2b = *(const v2f*)&b2[c2 + 2];
        v2f acc[4][2];
#pragma unroll
        for (int i = 0; i < 4; ++i) { acc[i][0] = b2a; acc[i][1] = b2b; }
        for (int k = 0; k < 256; k += 4) {
            v4f W0 = *(const v4f*)&W2[(size_t)(k + 0) * 128 + c2];
            v4f W1r = *(const v4f*)&W2[(size_t)(k + 1) * 128 + c2];
            v4f W2r = *(const v4f*)&W2[(size_t)(k + 2) * 128 + c2];
            v4f W3r = *(const v4f*)&W2[(size_t)(k + 3) * 128 + c2];
#pragma unroll
            for (int i = 0; i < 4; ++i) {
                v4f xv = *(const v4f*)&Xh[rg * 4 + i][k];
                acc[i][0] = __builtin_elementwise_fma(sp(xv.x), W0.xy, acc[i][0]);
                acc[i][1] = __builtin_elementwise_fma(sp(xv.x), W0.zw, acc[i][1]);
                acc[i][0] = __builtin_elementwise_fma(sp(xv.y), W1r.xy, acc[i][0]);
                acc[i][1] = __builtin_elementwise_fma(sp(xv.y), W1r.zw, acc[i][1]);
                acc[i][0] = __builtin_elementwise_fma(sp(xv.z), W2r.xy, acc[i][0]);
                acc[i][1] = __builtin_elementwise_fma(sp(xv.z), W2r.zw, acc[i][1]);
                acc[i][0] = __builtin_elementwise_fma(sp(xv.w), W3r.xy, acc[i][0]);
                acc[i][1] = __builtin_elementwise_fma(sp(xv.w), W3r.zw, acc[i][1]);
            }
        }
#pragma unroll
        for (int i = 0; i < 4; ++i) {
            int row = node0 + rg * 4 + i;
            if (row < N) {
                float4 o = make_float4(acc[i][0].x, acc[i][0].y, acc[i][1].x, acc[i][1].y);
                if (RES) {
                    float4 xo = *(const float4*)&xold[(size_t)row * 128 + c2];
                    o.x += xo.x; o.y += xo.y; o.z += xo.z; o.w += xo.w;
                }
                *(float4*)&xnew[(size_t)row * 128 + c2] = o;
            }
        }
    }
}

// ---------------------------------------------------------------- head
__global__ __launch_bounds__(256)
void head_kernel(const float* __restrict__ pre, const float* __restrict__ gf,
                 const float* __restrict__ W0, const float* __restrict__ b0,
                 const float* __restrict__ W1h, const float* __restrict__ b1h,
                 float* __restrict__ out, int N) {
    __shared__ __align__(16) float V[8][132];
    int tid = threadIdx.x;
    int node0 = blockIdx.x * 8;
    int tx = tid & 31, rg = tid >> 5;
    {
        int col = tx * 4;
        float4 v = make_float4(0, 0, 0, 0);
        int node = node0 + rg;
        if (node < N) v = *(const float4*)&pre[(size_t)node * 128 + col];
        *(float4*)&V[rg][col] = v;
        if (tx == 0) {
            int a = node / 1000;
            int i0 = 2 * a, i1 = 2 * a + 1;
            float f0 = 0.f, f1 = 0.f;
            if (node < N) {
                f0 = (i0 < 50) ? gf[i0 * 2] : gf[(i0 - 50) * 2 + 1];
                f1 = (i1 < 50) ? gf[i1 * 2] : gf[(i1 - 50) * 2 + 1];
            }
            V[rg][128] = f0;
            V[rg][129] = f1;
        }
    }
    __syncthreads();
    int c = tx * 4;
    float4 b0v = *(const float4*)&b0[c];
    float a0 = b0v.x, a1 = b0v.y, a2 = b0v.z, a3 = b0v.w;
    for (int k = 0; k < 130; ++k) {
        float vk = V[rg][k];
        float4 w = *(const float4*)&W0[k * 128 + c];
        a0 = fmaf(vk, w.x, a0);
        a1 = fmaf(vk, w.y, a1);
        a2 = fmaf(vk, w.z, a2);
        a3 = fmaf(vk, w.w, a3);
    }
    a0 = fmaxf(a0, 0.f); a1 = fmaxf(a1, 0.f); a2 = fmaxf(a2, 0.f); a3 = fmaxf(a3, 0.f);
    float4 wh = *(const float4*)&W1h[c];
    float p = a0 * wh.x + a1 * wh.y + a2 * wh.z + a3 * wh.w;
#pragma unroll
    for (int m = 1; m < 32; m <<= 1) p += __shfl_xor(p, m, 64);
    int node = node0 + rg;
    if (tx == 0 && node < N) out[node] = p + b1h[0];
}

// ---------------------------------------------------------------- launch
extern "C" void kernel_launch(void* const* d_in, const int* in_sizes, int n_in,
                              void* d_out, int out_size, void* d_ws, size_t ws_size,
                              hipStream_t stream) {
    const float* x_in    = (const float*)d_in[0];
    const int*   ei      = (const int*)d_in[1];
    const float* edge_attr = (const float*)d_in[2];
    const float* gf      = (const float*)d_in[3];
    const float* node_W  = (const float*)d_in[4];
    const float* node_b  = (const float*)d_in[5];
    const float* edge_W  = (const float*)d_in[6];
    const float* edge_b  = (const float*)d_in[7];
    const float* ts      = (const float*)d_in[8];
    const float* W1s     = (const float*)d_in[9];
    const float* b1s     = (const float*)d_in[10];
    const float* g1s     = (const float*)d_in[11];
    const float* be1s    = (const float*)d_in[12];
    const float* W2s     = (const float*)d_in[13];
    const float* b2s     = (const float*)d_in[14];
    const float* ln_gs   = (const float*)d_in[15];
    const float* ln_bs   = (const float*)d_in[16];
    const float* hW0     = (const float*)d_in[17];
    const float* hb0     = (const float*)d_in[18];
    const float* hW1     = (const float*)d_in[19];
    const float* hb1     = (const float*)d_in[20];

    const int N = in_sizes[0] / 64;
    const int E = in_sizes[1] / 2;
    const int NB = (N + 1023) / 1024;

    char* ws = (char*)d_ws;
    size_t off = 0;
    auto alloc = [&](size_t bytes) -> void* {
        void* p = ws + off;
        off = (off + bytes + 255) & ~(size_t)255;
        return p;
    };
    float* X     = (float*)alloc((size_t)N * 128 * 4);
    float* PRE   = (float*)alloc((size_t)N * 128 * 4);
    float* CONV  = (float*)alloc((size_t)N * 128 * 4);
    float* ATTRP = (float*)alloc((size_t)E * 16 * 4);
    int* SRCP    = (int*)alloc((size_t)E * 4);
    int* DEG     = (int*)alloc((size_t)N * 4);
    int* FILL    = (int*)alloc((size_t)N * 4);
    int* OFFS    = (int*)alloc((size_t)(N + 1) * 4);
    int* BSUM    = (int*)alloc((size_t)(NB + 1) * 4);

    // EA region: whatever workspace remains, 256 B per CSR edge slot.
    unsigned short* EAB = (unsigned short*)(ws + off);
    size_t avail = (ws_size > off) ? (ws_size - off) : 0;
    long long ecap = (long long)(avail / 256);
    int Ecut = (int)((ecap > (long long)E) ? E : ecap);

    // CSR build
    zero2_kernel<<<(N + 255) / 256, 256, 0, stream>>>(DEG, FILL, N);
    deg_kernel<<<(E + 255) / 256, 256, 0, stream>>>(ei, DEG, E);
    scan1_kernel<<<NB, 1024, 0, stream>>>(DEG, OFFS, BSUM, N);
    scan2_kernel<<<1, 64, 0, stream>>>(BSUM, NB);
    scan3_kernel<<<(N + 256) / 256, 256, 0, stream>>>(OFFS, BSUM, N);
    scatter_kernel<<<(E + 255) / 256, 256, 0, stream>>>(ei, edge_attr, OFFS, FILL, SRCP, ATTRP, E);
    if (Ecut > 0)
        ea_csr_kernel<<<(Ecut + 63) / 64, 256, 0, stream>>>(ATTRP, edge_W, edge_b, EAB, Ecut);

    encode_kernel<<<(N + 31) / 32, 256, 0, stream>>>(x_in, node_W, node_b, X, N);

    for (int layer = 0; layer < 4; ++layer) {
        const float* pre = X;
        if (layer > 0) {
            ln_relu_kernel<<<(N + 3) / 4, 256, 0, stream>>>(X, ln_gs + 128 * layer, ln_bs + 128 * layer, PRE, N);
            pre = PRE;
        }
        conv_kernel<<<(N + 3) / 4, 256, 0, stream>>>(pre, EAB, ATTRP, SRCP, OFFS, edge_W, edge_b,
                                                     ts, layer, Ecut, CONV, N);
        const float* W1 = W1s + (size_t)layer * 128 * 256;
        const float* W2 = W2s + (size_t)layer * 256 * 128;
        if (layer == 0)
            mlp_kernel<0><<<(N + 31) / 32, 256, 0, stream>>>(CONV, W1, b1s + layer * 256, g1s + layer * 256,
                                                             be1s + layer * 256, W2, b2s + layer * 128, X, X, N);
        else
            mlp_kernel<1><<<(N + 31) / 32, 256, 0, stream>>>(CONV, W1, b1s + layer * 256, g1s + layer * 256,
                                                             be1s + layer * 256, W2, b2s + layer * 128, X, X, N);
    }

    ln_relu_kernel<<<(N + 3) / 4, 256, 0, stream>>>(X, ln_gs, ln_bs, PRE, N);
    head_kernel<<<(N + 7) / 8, 256, 0, stream>>>(PRE, gf, hW0, hb0, hW1, hb1, (float*)d_out, N);
}

// Round 8
// 735.835 us; speedup vs baseline: 1.5742x; 1.5742x over previous
//
#include <hip/hip_runtime.h>
#include <math.h>

#define EPS_MSG 1e-7f

typedef float v2f __attribute__((ext_vector_type(2)));
typedef float v4f __attribute__((ext_vector_type(4)));
typedef short bf16x8 __attribute__((ext_vector_type(8)));
typedef float f32x4 __attribute__((ext_vector_type(4)));

static __device__ inline v2f sp(float a) { v2f r; r.x = a; r.y = a; return r; }

__device__ inline unsigned short f2bf(float f) {
    union { float f; unsigned int i; } u; u.f = f;
    unsigned int b = u.i;
    return (unsigned short)((b + 0x7fffu + ((b >> 16) & 1u)) >> 16);
}
__device__ inline float bf2f(unsigned short h) {
    union { unsigned int i; float f; } u; u.i = ((unsigned int)h) << 16;
    return u.f;
}

// ---------------------------------------------------------------- CSR build
__global__ void zero2_kernel(int* __restrict__ a, int* __restrict__ b, int n) {
    int i = blockIdx.x * 256 + threadIdx.x;
    if (i < n) { a[i] = 0; b[i] = 0; }
}

__global__ void deg_kernel(const int* __restrict__ ei, int* __restrict__ deg, int E) {
    int e = blockIdx.x * 256 + threadIdx.x;
    if (e < E) atomicAdd(&deg[ei[E + e]], 1);
}

__global__ __launch_bounds__(1024)
void scan1_kernel(const int* __restrict__ deg, int* __restrict__ offs,
                  int* __restrict__ bsum, int n) {
    __shared__ int sh[1024];
    int tid = threadIdx.x;
    int i = blockIdx.x * 1024 + tid;
    int v = (i < n) ? deg[i] : 0;
    sh[tid] = v;
    __syncthreads();
    for (int off = 1; off < 1024; off <<= 1) {
        int t = (tid >= off) ? sh[tid - off] : 0;
        __syncthreads();
        sh[tid] += t;
        __syncthreads();
    }
    if (i < n) offs[i] = sh[tid] - v;
    if (tid == 1023) bsum[blockIdx.x] = sh[tid];
}

__global__ __launch_bounds__(64)
void scan2_kernel(int* __restrict__ bsum, int nb) {
    int lane = threadIdx.x;
    int carry = 0;
    for (int base = 0; base < nb; base += 64) {
        int v = (base + lane < nb) ? bsum[base + lane] : 0;
        int incl = v;
#pragma unroll
        for (int off = 1; off < 64; off <<= 1) {
            int t = __shfl_up(incl, off, 64);
            if (lane >= off) incl += t;
        }
        if (base + lane < nb) bsum[base + lane] = incl - v + carry;
        carry += __shfl(incl, 63, 64);
    }
    if (lane == 0) bsum[nb] = carry;
}

__global__ void scan3_kernel(int* __restrict__ offs, const int* __restrict__ bsum, int n) {
    int i = blockIdx.x * 256 + threadIdx.x;
    if (i < n) offs[i] += bsum[i >> 10];
    else if (i == n) offs[n] = bsum[(n + 1023) >> 10];
}

__global__ void scatter_kernel(const int* __restrict__ ei, const float* __restrict__ edge_attr,
                               const int* __restrict__ offs, int* __restrict__ fill,
                               int* __restrict__ src_perm, float* __restrict__ attr_perm, int E) {
    int e = blockIdx.x * 256 + threadIdx.x;
    if (e >= E) return;
    int s = ei[e];
    int d = ei[E + e];
    int pos = offs[d] + atomicAdd(&fill[d], 1);
    src_perm[pos] = s;
    const float4* a = (const float4*)&edge_attr[(size_t)e * 16];
    float4* b = (float4*)&attr_perm[(size_t)pos * 16];
    b[0] = a[0]; b[1] = a[1]; b[2] = a[2]; b[3] = a[3];
}

// ---------------------------------------------------------------- weight swizzle into MFMA fragment order (hi/lo bf16)
// dst idx = ((l*(Ncol/16)+c16)*(K/32)+kstep)*512 + lane*8 + j
// src: k = kstep*32 + (lane>>4)*8 + j, n = c16*16 + (lane&15)
__global__ void wswz_kernel(const float* __restrict__ W, unsigned short* __restrict__ WH,
                            unsigned short* __restrict__ WL, int K, int Ncol, int total) {
    int idx = blockIdx.x * 256 + threadIdx.x;
    if (idx >= total) return;
    int j = idx & 7;
    int lane = (idx >> 3) & 63;
    int rest = idx >> 9;
    int ks = K >> 5;
    int kstep = rest % ks;
    int rest2 = rest / ks;
    int nc = Ncol >> 4;
    int c16 = rest2 % nc;
    int l = rest2 / nc;
    int k = kstep * 32 + (lane >> 4) * 8 + j;
    int n = c16 * 16 + (lane & 15);
    float v = W[(size_t)l * K * Ncol + (size_t)k * Ncol + n];
    unsigned short hi = f2bf(v);
    unsigned short lo = f2bf(v - bf2f(hi));
    WH[idx] = hi;
    WL[idx] = lo;
}

// ---------------------------------------------------------------- node encoder: X = x @ W(64x128) + b
__global__ __launch_bounds__(256)
void encode_kernel(const float* __restrict__ x, const float* __restrict__ W,
                   const float* __restrict__ b, float* __restrict__ out, int N) {
    __shared__ __align__(16) float Xa[32][64];
    int tid = threadIdx.x;
    int node0 = blockIdx.x * 32;
    {
        int row = tid >> 3;
        int col = (tid & 7) * 8;
        float4 v0 = make_float4(0, 0, 0, 0), v1 = make_float4(0, 0, 0, 0);
        if (node0 + row < N) {
            const float* sp_ = &x[(size_t)(node0 + row) * 64 + col];
            v0 = *(const float4*)sp_;
            v1 = *(const float4*)(sp_ + 4);
        }
        *(float4*)&Xa[row][col] = v0;
        *(float4*)&Xa[row][col + 4] = v1;
    }
    __syncthreads();
    int tx = tid & 31, rg = tid >> 5;
    int c = tx * 4;
    v2f ba = *(const v2f*)&b[c];
    v2f bb = *(const v2f*)&b[c + 2];
    v2f acc[4][2];
#pragma unroll
    for (int i = 0; i < 4; ++i) { acc[i][0] = ba; acc[i][1] = bb; }
    for (int k = 0; k < 64; k += 4) {
        v4f W0 = *(const v4f*)&W[(k + 0) * 128 + c];
        v4f W1r = *(const v4f*)&W[(k + 1) * 128 + c];
        v4f W2r = *(const v4f*)&W[(k + 2) * 128 + c];
        v4f W3r = *(const v4f*)&W[(k + 3) * 128 + c];
#pragma unroll
        for (int i = 0; i < 4; ++i) {
            v4f xv = *(const v4f*)&Xa[rg * 4 + i][k];
            acc[i][0] = __builtin_elementwise_fma(sp(xv.x), W0.xy, acc[i][0]);
            acc[i][1] = __builtin_elementwise_fma(sp(xv.x), W0.zw, acc[i][1]);
            acc[i][0] = __builtin_elementwise_fma(sp(xv.y), W1r.xy, acc[i][0]);
            acc[i][1] = __builtin_elementwise_fma(sp(xv.y), W1r.zw, acc[i][1]);
            acc[i][0] = __builtin_elementwise_fma(sp(xv.z), W2r.xy, acc[i][0]);
            acc[i][1] = __builtin_elementwise_fma(sp(xv.z), W2r.zw, acc[i][1]);
            acc[i][0] = __builtin_elementwise_fma(sp(xv.w), W3r.xy, acc[i][0]);
            acc[i][1] = __builtin_elementwise_fma(sp(xv.w), W3r.zw, acc[i][1]);
        }
    }
#pragma unroll
    for (int i = 0; i < 4; ++i) {
        int row = node0 + rg * 4 + i;
        if (row < N) {
            float4 o = make_float4(acc[i][0].x, acc[i][0].y, acc[i][1].x, acc[i][1].y);
            *(float4*)&out[(size_t)row * 128 + c] = o;
        }
    }
}

// ---------------------------------------------------------------- LN(128) + relu
__global__ __launch_bounds__(256)
void ln_relu_kernel(const float* __restrict__ x, const float* __restrict__ g,
                    const float* __restrict__ b, float* __restrict__ out, int N) {
    int lane = threadIdx.x & 63;
    int node = blockIdx.x * 4 + (threadIdx.x >> 6);
    if (node >= N) return;
    int c0 = lane * 2;
    float2 xv = *(const float2*)&x[(size_t)node * 128 + c0];
    float s = xv.x + xv.y;
    float q = xv.x * xv.x + xv.y * xv.y;
#pragma unroll
    for (int m = 1; m < 64; m <<= 1) { s += __shfl_xor(s, m, 64); q += __shfl_xor(q, m, 64); }
    float mu = s * (1.f / 128.f);
    float var = q * (1.f / 128.f) - mu * mu;
    float rs = rsqrtf(var + 1e-5f);
    float ox = fmaxf((xv.x - mu) * rs * g[c0] + b[c0], 0.f);
    float oy = fmaxf((xv.y - mu) * rs * g[c0 + 1] + b[c0 + 1], 0.f);
    float2 o; o.x = ox; o.y = oy;
    *(float2*)&out[(size_t)node * 128 + c0] = o;
}

// ---------------------------------------------------------------- GENConv aggregation (R6 structure; hi/lo bf16 output)
__global__ __launch_bounds__(256, 4)
void conv_kernel(const float* __restrict__ pre, const float* __restrict__ attr_perm,
                 const int* __restrict__ src_perm, const int* __restrict__ offs,
                 const float* __restrict__ edge_W, const float* __restrict__ edge_b,
                 const float* __restrict__ ts, int layer,
                 unsigned short* __restrict__ convH, unsigned short* __restrict__ convL, int N) {
    int lane = threadIdx.x & 63;
    int node = blockIdx.x * 4 + (threadIdx.x >> 6);
    if (node >= N) return;
    int c0 = lane * 2;
    v2f wE[16];
#pragma unroll
    for (int k = 0; k < 16; ++k) {
        wE[k].x = edge_W[k * 128 + c0];
        wE[k].y = edge_W[k * 128 + c0 + 1];
    }
    v2f eb; eb.x = edge_b[c0]; eb.y = edge_b[c0 + 1];
    float t = ts[layer];
    int i0 = offs[node], i1 = offs[node + 1];
    v2f xself = *(const v2f*)&pre[(size_t)node * 128 + c0];
    float sx = 0.f, sy = 0.f, wx = 0.f, wy = 0.f;
    int i = i0;
    for (; i + 1 < i1; i += 2) {
        int iu = __builtin_amdgcn_readfirstlane(i);
        int sa = src_perm[iu];
        int sb = src_perm[iu + 1];
        const v4f* ar = (const v4f*)(attr_perm + (size_t)iu * 16);
        v4f A0 = ar[0], A1 = ar[1], A2 = ar[2], A3 = ar[3];
        v4f B0 = ar[4], B1 = ar[5], B2 = ar[6], B3 = ar[7];
        v2f xa = *(const v2f*)&pre[(size_t)sa * 128 + c0];
        v2f xb = *(const v2f*)&pre[(size_t)sb * 128 + c0];
        v2f ea = eb, eb2 = eb;
        ea  = __builtin_elementwise_fma(sp(A0.x), wE[0], ea);
        eb2 = __builtin_elementwise_fma(sp(B0.x), wE[0], eb2);
        ea  = __builtin_elementwise_fma(sp(A0.y), wE[1], ea);
        eb2 = __builtin_elementwise_fma(sp(B0.y), wE[1], eb2);
        ea  = __builtin_elementwise_fma(sp(A0.z), wE[2], ea);
        eb2 = __builtin_elementwise_fma(sp(B0.z), wE[2], eb2);
        ea  = __builtin_elementwise_fma(sp(A0.w), wE[3], ea);
        eb2 = __builtin_elementwise_fma(sp(B0.w), wE[3], eb2);
        ea  = __builtin_elementwise_fma(sp(A1.x), wE[4], ea);
        eb2 = __builtin_elementwise_fma(sp(B1.x), wE[4], eb2);
        ea  = __builtin_elementwise_fma(sp(A1.y), wE[5], ea);
        eb2 = __builtin_elementwise_fma(sp(B1.y), wE[5], eb2);
        ea  = __builtin_elementwise_fma(sp(A1.z), wE[6], ea);
        eb2 = __builtin_elementwise_fma(sp(B1.z), wE[6], eb2);
        ea  = __builtin_elementwise_fma(sp(A1.w), wE[7], ea);
        eb2 = __builtin_elementwise_fma(sp(B1.w), wE[7], eb2);
        ea  = __builtin_elementwise_fma(sp(A2.x), wE[8], ea);
        eb2 = __builtin_elementwise_fma(sp(B2.x), wE[8], eb2);
        ea  = __builtin_elementwise_fma(sp(A2.y), wE[9], ea);
        eb2 = __builtin_elementwise_fma(sp(B2.y), wE[9], eb2);
        ea  = __builtin_elementwise_fma(sp(A2.z), wE[10], ea);
        eb2 = __builtin_elementwise_fma(sp(B2.z), wE[10], eb2);
        ea  = __builtin_elementwise_fma(sp(A2.w), wE[11], ea);
        eb2 = __builtin_elementwise_fma(sp(B2.w), wE[11], eb2);
        ea  = __builtin_elementwise_fma(sp(A3.x), wE[12], ea);
        eb2 = __builtin_elementwise_fma(sp(B3.x), wE[12], eb2);
        ea  = __builtin_elementwise_fma(sp(A3.y), wE[13], ea);
        eb2 = __builtin_elementwise_fma(sp(B3.y), wE[13], eb2);
        ea  = __builtin_elementwise_fma(sp(A3.z), wE[14], ea);
        eb2 = __builtin_elementwise_fma(sp(B3.z), wE[14], eb2);
        ea  = __builtin_elementwise_fma(sp(A3.w), wE[15], ea);
        eb2 = __builtin_elementwise_fma(sp(B3.w), wE[15], eb2);
        float mgax = fmaxf(xa.x + ea.x, 0.f) + EPS_MSG;
        float mgay = fmaxf(xa.y + ea.y, 0.f) + EPS_MSG;
        float mgbx = fmaxf(xb.x + eb2.x, 0.f) + EPS_MSG;
        float mgby = fmaxf(xb.y + eb2.y, 0.f) + EPS_MSG;
        float exa = __expf(mgax * t), eya = __expf(mgay * t);
        float exb = __expf(mgbx * t), eyb = __expf(mgby * t);
        sx += exa + exb; sy += eya + eyb;
        wx = fmaf(exa, mgax, wx); wx = fmaf(exb, mgbx, wx);
        wy = fmaf(eya, mgay, wy); wy = fmaf(eyb, mgby, wy);
    }
    if (i < i1) {
        int iu = __builtin_amdgcn_readfirstlane(i);
        int sn = src_perm[iu];
        const v4f* ar = (const v4f*)(attr_perm + (size_t)iu * 16);
        v4f A0 = ar[0], A1 = ar[1], A2 = ar[2], A3 = ar[3];
        v2f xv = *(const v2f*)&pre[(size_t)sn * 128 + c0];
        v2f ea = eb;
        ea = __builtin_elementwise_fma(sp(A0.x), wE[0], ea);
        ea = __builtin_elementwise_fma(sp(A0.y), wE[1], ea);
        ea = __builtin_elementwise_fma(sp(A0.z), wE[2], ea);
        ea = __builtin_elementwise_fma(sp(A0.w), wE[3], ea);
        ea = __builtin_elementwise_fma(sp(A1.x), wE[4], ea);
        ea = __builtin_elementwise_fma(sp(A1.y), wE[5], ea);
        ea = __builtin_elementwise_fma(sp(A1.z), wE[6], ea);
        ea = __builtin_elementwise_fma(sp(A1.w), wE[7], ea);
        ea = __builtin_elementwise_fma(sp(A2.x), wE[8], ea);
        ea = __builtin_elementwise_fma(sp(A2.y), wE[9], ea);
        ea = __builtin_elementwise_fma(sp(A2.z), wE[10], ea);
        ea = __builtin_elementwise_fma(sp(A2.w), wE[11], ea);
        ea = __builtin_elementwise_fma(sp(A3.x), wE[12], ea);
        ea = __builtin_elementwise_fma(sp(A3.y), wE[13], ea);
        ea = __builtin_elementwise_fma(sp(A3.z), wE[14], ea);
        ea = __builtin_elementwise_fma(sp(A3.w), wE[15], ea);
        float mgx = fmaxf(xv.x + ea.x, 0.f) + EPS_MSG;
        float mgy = fmaxf(xv.y + ea.y, 0.f) + EPS_MSG;
        float ex = __expf(mgx * t), ey = __expf(mgy * t);
        sx += ex; sy += ey;
        wx = fmaf(ex, mgx, wx);
        wy = fmaf(ey, mgy, wy);
    }
    float ax = (sx > 0.f) ? wx / sx : 0.f;
    float ay = (sy > 0.f) ? wy / sy : 0.f;
    float ox = ax + xself.x;
    float oy = ay + xself.y;
    unsigned short hx = f2bf(ox), hy = f2bf(oy);
    unsigned short lx = f2bf(ox - bf2f(hx)), ly = f2bf(oy - bf2f(hy));
    *(unsigned int*)&convH[(size_t)node * 128 + c0] = (unsigned int)hx | ((unsigned int)hy << 16);
    *(unsigned int*)&convL[(size_t)node * 128 + c0] = (unsigned int)lx | ((unsigned int)ly << 16);
}

// ---------------------------------------------------------------- fused MLP via MFMA (split hi/lo bf16, exact to ~2^-16)
// Block: 32 nodes. GEMM1 32x256 (K=128), LN+relu, GEMM2 32x128 (K=256), +residual.
// A-frag: row=lane&15, k=(lane>>4)*8+j ; B-frag pre-swizzled ; C/D: col=lane&15, row=(lane>>4)*4+reg.
template <int RES>
__global__ __launch_bounds__(256)
void mlp_mfma(const unsigned short* __restrict__ convH, const unsigned short* __restrict__ convL,
              const unsigned short* __restrict__ W1H, const unsigned short* __restrict__ W1L,
              const float* __restrict__ b1, const float* __restrict__ g1, const float* __restrict__ be1,
              const unsigned short* __restrict__ W2H, const unsigned short* __restrict__ W2L,
              const float* __restrict__ b2, const float* __restrict__ xold,
              float* __restrict__ xnew, int N) {
    __shared__ __align__(16) unsigned short XaH[32][136];
    __shared__ __align__(16) unsigned short XaL[32][136];
    __shared__ __align__(16) unsigned short XhH[32][264];
    __shared__ __align__(16) unsigned short XhL[32][264];
    __shared__ float2 ps[4][32];
    int tid = threadIdx.x;
    int w = tid >> 6;
    int lane = tid & 63;
    int g = lane >> 4;
    int r = lane & 15;
    int node0 = blockIdx.x * 32;
    // stage input tile (bf16 hi/lo)
    {
        int row = tid >> 3;
        int cb = (tid & 7) * 16;
        uint4 h0 = make_uint4(0, 0, 0, 0), h1 = h0, l0 = h0, l1 = h0;
        if (node0 + row < N) {
            const uint4* pH = (const uint4*)&convH[(size_t)(node0 + row) * 128 + cb];
            const uint4* pL = (const uint4*)&convL[(size_t)(node0 + row) * 128 + cb];
            h0 = pH[0]; h1 = pH[1];
            l0 = pL[0]; l1 = pL[1];
        }
        *(uint4*)&XaH[row][cb] = h0; *(uint4*)&XaH[row][cb + 8] = h1;
        *(uint4*)&XaL[row][cb] = l0; *(uint4*)&XaL[row][cb + 8] = l1;
    }
    __syncthreads();
    // ---------------- GEMM1: acc1[rf][cf], wave w covers cols 64w..64w+63
    f32x4 acc1[2][4];
#pragma unroll
    for (int cf = 0; cf < 4; ++cf) {
        float bv = b1[(w * 4 + cf) * 16 + r];
        f32x4 iv; iv[0] = bv; iv[1] = bv; iv[2] = bv; iv[3] = bv;
        acc1[0][cf] = iv; acc1[1][cf] = iv;
    }
#pragma unroll
    for (int kstep = 0; kstep < 4; ++kstep) {
        int ko = kstep * 32 + g * 8;
        bf16x8 aH0 = *(const bf16x8*)&XaH[r][ko];
        bf16x8 aH1 = *(const bf16x8*)&XaH[16 + r][ko];
        bf16x8 aL0 = *(const bf16x8*)&XaL[r][ko];
        bf16x8 aL1 = *(const bf16x8*)&XaL[16 + r][ko];
#pragma unroll
        for (int cf = 0; cf < 4; ++cf) {
            int c16 = w * 4 + cf;
            bf16x8 bH = *(const bf16x8*)&W1H[(((size_t)c16 * 4 + kstep) * 64 + lane) * 8];
            bf16x8 bL = *(const bf16x8*)&W1L[(((size_t)c16 * 4 + kstep) * 64 + lane) * 8];
            acc1[0][cf] = __builtin_amdgcn_mfma_f32_16x16x32_bf16(aH0, bH, acc1[0][cf], 0, 0, 0);
            acc1[0][cf] = __builtin_amdgcn_mfma_f32_16x16x32_bf16(aH0, bL, acc1[0][cf], 0, 0, 0);
            acc1[0][cf] = __builtin_amdgcn_mfma_f32_16x16x32_bf16(aL0, bH, acc1[0][cf], 0, 0, 0);
            acc1[1][cf] = __builtin_amdgcn_mfma_f32_16x16x32_bf16(aH1, bH, acc1[1][cf], 0, 0, 0);
            acc1[1][cf] = __builtin_amdgcn_mfma_f32_16x16x32_bf16(aH1, bL, acc1[1][cf], 0, 0, 0);
            acc1[1][cf] = __builtin_amdgcn_mfma_f32_16x16x32_bf16(aL1, bH, acc1[1][cf], 0, 0, 0);
        }
    }
    // ---------------- LN(256)+relu ; value (row = rf*16+g*4+reg, col = (4w+cf)*16+r)
    {
        float s_[2][4], q_[2][4];
#pragma unroll
        for (int rf = 0; rf < 2; ++rf)
#pragma unroll
            for (int reg = 0; reg < 4; ++reg) {
                float s = 0.f, q = 0.f;
#pragma unroll
                for (int cf = 0; cf < 4; ++cf) {
                    float v = acc1[rf][cf][reg];
                    s += v; q += v * v;
                }
                s_[rf][reg] = s; q_[rf][reg] = q;
            }
#pragma unroll
        for (int m = 1; m < 16; m <<= 1) {
#pragma unroll
            for (int rf = 0; rf < 2; ++rf)
#pragma unroll
                for (int reg = 0; reg < 4; ++reg) {
                    s_[rf][reg] += __shfl_xor(s_[rf][reg], m, 64);
                    q_[rf][reg] += __shfl_xor(q_[rf][reg], m, 64);
                }
        }
        if (r == 0) {
#pragma unroll
            for (int rf = 0; rf < 2; ++rf)
#pragma unroll
                for (int reg = 0; reg < 4; ++reg)
                    ps[w][rf * 16 + g * 4 + reg] = make_float2(s_[rf][reg], q_[rf][reg]);
        }
    }
    __syncthreads();
    {
        float gv[4], bev[4];
#pragma unroll
        for (int cf = 0; cf < 4; ++cf) {
            gv[cf] = g1[(w * 4 + cf) * 16 + r];
            bev[cf] = be1[(w * 4 + cf) * 16 + r];
        }
#pragma unroll
        for (int rf = 0; rf < 2; ++rf)
#pragma unroll
            for (int reg = 0; reg < 4; ++reg) {
                int row = rf * 16 + g * 4 + reg;
                float2 t0 = ps[0][row], t1 = ps[1][row], t2 = ps[2][row], t3 = ps[3][row];
                float s = t0.x + t1.x + t2.x + t3.x;
                float q = t0.y + t1.y + t2.y + t3.y;
                float mu = s * (1.f / 256.f);
                float var = q * (1.f / 256.f) - mu * mu;
                float rs = rsqrtf(var + 1e-5f);
#pragma unroll
                for (int cf = 0; cf < 4; ++cf) {
                    float h = fmaxf((acc1[rf][cf][reg] - mu) * rs * gv[cf] + bev[cf], 0.f);
                    unsigned short hh = f2bf(h);
                    unsigned short hl = f2bf(h - bf2f(hh));
                    int col = (w * 4 + cf) * 16 + r;
                    XhH[row][col] = hh;
                    XhL[row][col] = hl;
                }
            }
    }
    __syncthreads();
    // ---------------- GEMM2: wave w covers cols 32w..32w+31
    f32x4 acc2[2][2];
#pragma unroll
    for (int cf = 0; cf < 2; ++cf) {
        float bv = b2[(w * 2 + cf) * 16 + r];
        f32x4 iv; iv[0] = bv; iv[1] = bv; iv[2] = bv; iv[3] = bv;
        acc2[0][cf] = iv; acc2[1][cf] = iv;
    }
#pragma unroll
    for (int kstep = 0; kstep < 8; ++kstep) {
        int ko = kstep * 32 + g * 8;
        bf16x8 aH0 = *(const bf16x8*)&XhH[r][ko];
        bf16x8 aH1 = *(const bf16x8*)&XhH[16 + r][ko];
        bf16x8 aL0 = *(const bf16x8*)&XhL[r][ko];
        bf16x8 aL1 = *(const bf16x8*)&XhL[16 + r][ko];
#pragma unroll
        for (int cf = 0; cf < 2; ++cf) {
            int c16 = w * 2 + cf;
            bf16x8 bH = *(const bf16x8*)&W2H[(((size_t)c16 * 8 + kstep) * 64 + lane) * 8];
            bf16x8 bL = *(const bf16x8*)&W2L[(((size_t)c16 * 8 + kstep) * 64 + lane) * 8];
            acc2[0][cf] = __builtin_amdgcn_mfma_f32_16x16x32_bf16(aH0, bH, acc2[0][cf], 0, 0, 0);
            acc2[0][cf] = __builtin_amdgcn_mfma_f32_16x16x32_bf16(aH0, bL, acc2[0][cf], 0, 0, 0);
            acc2[0][cf] = __builtin_amdgcn_mfma_f32_16x16x32_bf16(aL0, bH, acc2[0][cf], 0, 0, 0);
            acc2[1][cf] = __builtin_amdgcn_mfma_f32_16x16x32_bf16(aH1, bH, acc2[1][cf], 0, 0, 0);
            acc2[1][cf] = __builtin_amdgcn_mfma_f32_16x16x32_bf16(aH1, bL, acc2[1][cf], 0, 0, 0);
            acc2[1][cf] = __builtin_amdgcn_mfma_f32_16x16x32_bf16(aL1, bH, acc2[1][cf], 0, 0, 0);
        }
    }
    // ---------------- epilogue: + residual, store f32
#pragma unroll
    for (int rf = 0; rf < 2; ++rf)
#pragma unroll
        for (int reg = 0; reg < 4; ++reg) {
            int row = node0 + rf * 16 + g * 4 + reg;
            if (row < N) {
#pragma unroll
                for (int cf = 0; cf < 2; ++cf) {
                    int col = (w * 2 + cf) * 16 + r;
                    float v = acc2[rf][cf][reg];
                    if (RES) v += xold[(size_t)row * 128 + col];
                    xnew[(size_t)row * 128 + col] = v;
                }
            }
        }
}

// ---------------------------------------------------------------- head
__global__ __launch_bounds__(256)
void head_kernel(const float* __restrict__ pre, const float* __restrict__ gf,
                 const float* __restrict__ W0, const float* __restrict__ b0,
                 const float* __restrict__ W1h, const float* __restrict__ b1h,
                 float* __restrict__ out, int N) {
    __shared__ __align__(16) float V[8][132];
    int tid = threadIdx.x;
    int node0 = blockIdx.x * 8;
    int tx = tid & 31, rg = tid >> 5;
    {
        int col = tx * 4;
        float4 v = make_float4(0, 0, 0, 0);
        int node = node0 + rg;
        if (node < N) v = *(const float4*)&pre[(size_t)node * 128 + col];
        *(float4*)&V[rg][col] = v;
        if (tx == 0) {
            int a = node / 1000;
            int i0 = 2 * a, i1 = 2 * a + 1;
            float f0 = 0.f, f1 = 0.f;
            if (node < N) {
                f0 = (i0 < 50) ? gf[i0 * 2] : gf[(i0 - 50) * 2 + 1];
                f1 = (i1 < 50) ? gf[i1 * 2] : gf[(i1 - 50) * 2 + 1];
            }
            V[rg][128] = f0;
            V[rg][129] = f1;
        }
    }
    __syncthreads();
    int c = tx * 4;
    float4 b0v = *(const float4*)&b0[c];
    float a0 = b0v.x, a1 = b0v.y, a2 = b0v.z, a3 = b0v.w;
    for (int k = 0; k < 130; ++k) {
        float vk = V[rg][k];
        float4 wv = *(const float4*)&W0[k * 128 + c];
        a0 = fmaf(vk, wv.x, a0);
        a1 = fmaf(vk, wv.y, a1);
        a2 = fmaf(vk, wv.z, a2);
        a3 = fmaf(vk, wv.w, a3);
    }
    a0 = fmaxf(a0, 0.f); a1 = fmaxf(a1, 0.f); a2 = fmaxf(a2, 0.f); a3 = fmaxf(a3, 0.f);
    float4 wh = *(const float4*)&W1h[c];
    float p = a0 * wh.x + a1 * wh.y + a2 * wh.z + a3 * wh.w;
#pragma unroll
    for (int m = 1; m < 32; m <<= 1) p += __shfl_xor(p, m, 64);
    int node = node0 + rg;
    if (tx == 0 && node < N) out[node] = p + b1h[0];
}

// ---------------------------------------------------------------- launch
extern "C" void kernel_launch(void* const* d_in, const int* in_sizes, int n_in,
                              void* d_out, int out_size, void* d_ws, size_t ws_size,
                              hipStream_t stream) {
    const float* x_in    = (const float*)d_in[0];
    const int*   ei      = (const int*)d_in[1];
    const float* edge_attr = (const float*)d_in[2];
    const float* gf      = (const float*)d_in[3];
    const float* node_W  = (const float*)d_in[4];
    const float* node_b  = (const float*)d_in[5];
    const float* edge_W  = (const float*)d_in[6];
    const float* edge_b  = (const float*)d_in[7];
    const float* ts      = (const float*)d_in[8];
    const float* W1s     = (const float*)d_in[9];
    const float* b1s     = (const float*)d_in[10];
    const float* g1s     = (const float*)d_in[11];
    const float* be1s    = (const float*)d_in[12];
    const float* W2s     = (const float*)d_in[13];
    const float* b2s     = (const float*)d_in[14];
    const float* ln_gs   = (const float*)d_in[15];
    const float* ln_bs   = (const float*)d_in[16];
    const float* hW0     = (const float*)d_in[17];
    const float* hb0     = (const float*)d_in[18];
    const float* hW1     = (const float*)d_in[19];
    const float* hb1     = (const float*)d_in[20];

    const int N = in_sizes[0] / 64;
    const int E = in_sizes[1] / 2;
    const int NB = (N + 1023) / 1024;

    char* ws = (char*)d_ws;
    size_t off = 0;
    auto alloc = [&](size_t bytes) -> void* {
        void* p = ws + off;
        off = (off + bytes + 255) & ~(size_t)255;
        return p;
    };
    float* X     = (float*)alloc((size_t)N * 128 * 4);
    float* PRE   = (float*)alloc((size_t)N * 128 * 4);
    unsigned short* CONVH = (unsigned short*)alloc((size_t)N * 128 * 2);
    unsigned short* CONVL = (unsigned short*)alloc((size_t)N * 128 * 2);
    unsigned short* W1H = (unsigned short*)alloc((size_t)4 * 128 * 256 * 2);
    unsigned short* W1L = (unsigned short*)alloc((size_t)4 * 128 * 256 * 2);
    unsigned short* W2H = (unsigned short*)alloc((size_t)4 * 256 * 128 * 2);
    unsigned short* W2L = (unsigned short*)alloc((size_t)4 * 256 * 128 * 2);
    int* SRCP    = (int*)alloc((size_t)E * 4);
    int* DEG     = (int*)alloc((size_t)N * 4);
    int* FILL    = (int*)alloc((size_t)N * 4);
    int* OFFS    = (int*)alloc((size_t)(N + 1) * 4);
    int* BSUM    = (int*)alloc((size_t)(NB + 1) * 4);
    float* ATTRP = (float*)alloc((size_t)E * 16 * 4);

    // weight swizzle (once per call)
    const int TOT = 4 * 128 * 256;
    wswz_kernel<<<(TOT + 255) / 256, 256, 0, stream>>>(W1s, W1H, W1L, 128, 256, TOT);
    wswz_kernel<<<(TOT + 255) / 256, 256, 0, stream>>>(W2s, W2H, W2L, 256, 128, TOT);

    // CSR build
    zero2_kernel<<<(N + 255) / 256, 256, 0, stream>>>(DEG, FILL, N);
    deg_kernel<<<(E + 255) / 256, 256, 0, stream>>>(ei, DEG, E);
    scan1_kernel<<<NB, 1024, 0, stream>>>(DEG, OFFS, BSUM, N);
    scan2_kernel<<<1, 64, 0, stream>>>(BSUM, NB);
    scan3_kernel<<<(N + 256) / 256, 256, 0, stream>>>(OFFS, BSUM, N);
    scatter_kernel<<<(E + 255) / 256, 256, 0, stream>>>(ei, edge_attr, OFFS, FILL, SRCP, ATTRP, E);

    encode_kernel<<<(N + 31) / 32, 256, 0, stream>>>(x_in, node_W, node_b, X, N);

    for (int layer = 0; layer < 4; ++layer) {
        const float* pre = X;
        if (layer > 0) {
            ln_relu_kernel<<<(N + 3) / 4, 256, 0, stream>>>(X, ln_gs + 128 * layer, ln_bs + 128 * layer, PRE, N);
            pre = PRE;
        }
        conv_kernel<<<(N + 3) / 4, 256, 0, stream>>>(pre, ATTRP, SRCP, OFFS, edge_W, edge_b,
                                                     ts, layer, CONVH, CONVL, N);
        const unsigned short* w1h = W1H + (size_t)layer * 128 * 256;
        const unsigned short* w1l = W1L + (size_t)layer * 128 * 256;
        const unsigned short* w2h = W2H + (size_t)layer * 256 * 128;
        const unsigned short* w2l = W2L + (size_t)layer * 256 * 128;
        if (layer == 0)
            mlp_mfma<0><<<(N + 31) / 32, 256, 0, stream>>>(CONVH, CONVL, w1h, w1l,
                                                           b1s + layer * 256, g1s + layer * 256, be1s + layer * 256,
                                                           w2h, w2l, b2s + layer * 128, X, X, N);
        else
            mlp_mfma<1><<<(N + 31) / 32, 256, 0, stream>>>(CONVH, CONVL, w1h, w1l,
                                                           b1s + layer * 256, g1s + layer * 256, be1s + layer * 256,
                                                           w2h, w2l, b2s + layer * 128, X, X, N);
    }

    ln_relu_kernel<<<(N + 3) / 4, 256, 0, stream>>>(X, ln_gs, ln_bs, PRE, N);
    head_kernel<<<(N + 7) / 8, 256, 0, stream>>>(PRE, gf, hW0, hb0, hW1, hb1, (float*)d_out, N);
}

// Round 9
// 662.555 us; speedup vs baseline: 1.7484x; 1.1106x over previous
//
#include <hip/hip_runtime.h>
#include <math.h>

#define EPS_MSG 1e-7f

typedef float v2f __attribute__((ext_vector_type(2)));
typedef float v4f __attribute__((ext_vector_type(4)));
typedef short bf16x8 __attribute__((ext_vector_type(8)));
typedef float f32x4 __attribute__((ext_vector_type(4)));

static __device__ inline v2f sp(float a) { v2f r; r.x = a; r.y = a; return r; }

__device__ inline unsigned short f2bf(float f) {
    union { float f; unsigned int i; } u; u.f = f;
    unsigned int b = u.i;
    return (unsigned short)((b + 0x7fffu + ((b >> 16) & 1u)) >> 16);
}
__device__ inline float bf2f(unsigned short h) {
    union { unsigned int i; float f; } u; u.i = ((unsigned int)h) << 16;
    return u.f;
}

// ---------------------------------------------------------------- CSR build
__global__ void zero2_kernel(int* __restrict__ a, int* __restrict__ b, int n) {
    int i = blockIdx.x * 256 + threadIdx.x;
    if (i < n) { a[i] = 0; b[i] = 0; }
}

__global__ void deg_kernel(const int* __restrict__ ei, int* __restrict__ deg, int E) {
    int e = blockIdx.x * 256 + threadIdx.x;
    if (e < E) atomicAdd(&deg[ei[E + e]], 1);
}

__global__ __launch_bounds__(1024)
void scan1_kernel(const int* __restrict__ deg, int* __restrict__ offs,
                  int* __restrict__ bsum, int n) {
    __shared__ int sh[1024];
    int tid = threadIdx.x;
    int i = blockIdx.x * 1024 + tid;
    int v = (i < n) ? deg[i] : 0;
    sh[tid] = v;
    __syncthreads();
    for (int off = 1; off < 1024; off <<= 1) {
        int t = (tid >= off) ? sh[tid - off] : 0;
        __syncthreads();
        sh[tid] += t;
        __syncthreads();
    }
    if (i < n) offs[i] = sh[tid] - v;
    if (tid == 1023) bsum[blockIdx.x] = sh[tid];
}

__global__ __launch_bounds__(64)
void scan2_kernel(int* __restrict__ bsum, int nb) {
    int lane = threadIdx.x;
    int carry = 0;
    for (int base = 0; base < nb; base += 64) {
        int v = (base + lane < nb) ? bsum[base + lane] : 0;
        int incl = v;
#pragma unroll
        for (int off = 1; off < 64; off <<= 1) {
            int t = __shfl_up(incl, off, 64);
            if (lane >= off) incl += t;
        }
        if (base + lane < nb) bsum[base + lane] = incl - v + carry;
        carry += __shfl(incl, 63, 64);
    }
    if (lane == 0) bsum[nb] = carry;
}

__global__ void scan3_kernel(int* __restrict__ offs, const int* __restrict__ bsum, int n) {
    int i = blockIdx.x * 256 + threadIdx.x;
    if (i < n) offs[i] += bsum[i >> 10];
    else if (i == n) offs[n] = bsum[(n + 1023) >> 10];
}

__global__ void scatter_kernel(const int* __restrict__ ei, const float* __restrict__ edge_attr,
                               const int* __restrict__ offs, int* __restrict__ fill,
                               int* __restrict__ src_perm, float* __restrict__ attr_perm, int E) {
    int e = blockIdx.x * 256 + threadIdx.x;
    if (e >= E) return;
    int s = ei[e];
    int d = ei[E + e];
    int pos = offs[d] + atomicAdd(&fill[d], 1);
    src_perm[pos] = s;
    const float4* a = (const float4*)&edge_attr[(size_t)e * 16];
    float4* b = (float4*)&attr_perm[(size_t)pos * 16];
    b[0] = a[0]; b[1] = a[1]; b[2] = a[2]; b[3] = a[3];
}

// ---------------------------------------------------------------- weight swizzle into MFMA fragment order (hi/lo bf16)
__global__ void wswz_kernel(const float* __restrict__ W, unsigned short* __restrict__ WH,
                            unsigned short* __restrict__ WL, int K, int Ncol, int total) {
    int idx = blockIdx.x * 256 + threadIdx.x;
    if (idx >= total) return;
    int j = idx & 7;
    int lane = (idx >> 3) & 63;
    int rest = idx >> 9;
    int ks = K >> 5;
    int kstep = rest % ks;
    int rest2 = rest / ks;
    int nc = Ncol >> 4;
    int c16 = rest2 % nc;
    int l = rest2 / nc;
    int k = kstep * 32 + (lane >> 4) * 8 + j;
    int n = c16 * 16 + (lane & 15);
    float v = W[(size_t)l * K * Ncol + (size_t)k * Ncol + n];
    unsigned short hi = f2bf(v);
    unsigned short lo = f2bf(v - bf2f(hi));
    WH[idx] = hi;
    WL[idx] = lo;
}

// ---------------------------------------------------------------- node encoder: X = x @ W(64x128) + b
__global__ __launch_bounds__(256)
void encode_kernel(const float* __restrict__ x, const float* __restrict__ W,
                   const float* __restrict__ b, float* __restrict__ out, int N) {
    __shared__ __align__(16) float Xa[32][64];
    int tid = threadIdx.x;
    int node0 = blockIdx.x * 32;
    {
        int row = tid >> 3;
        int col = (tid & 7) * 8;
        float4 v0 = make_float4(0, 0, 0, 0), v1 = make_float4(0, 0, 0, 0);
        if (node0 + row < N) {
            const float* sp_ = &x[(size_t)(node0 + row) * 64 + col];
            v0 = *(const float4*)sp_;
            v1 = *(const float4*)(sp_ + 4);
        }
        *(float4*)&Xa[row][col] = v0;
        *(float4*)&Xa[row][col + 4] = v1;
    }
    __syncthreads();
    int tx = tid & 31, rg = tid >> 5;
    int c = tx * 4;
    v2f ba = *(const v2f*)&b[c];
    v2f bb = *(const v2f*)&b[c + 2];
    v2f acc[4][2];
#pragma unroll
    for (int i = 0; i < 4; ++i) { acc[i][0] = ba; acc[i][1] = bb; }
    for (int k = 0; k < 64; k += 4) {
        v4f W0 = *(const v4f*)&W[(k + 0) * 128 + c];
        v4f W1r = *(const v4f*)&W[(k + 1) * 128 + c];
        v4f W2r = *(const v4f*)&W[(k + 2) * 128 + c];
        v4f W3r = *(const v4f*)&W[(k + 3) * 128 + c];
#pragma unroll
        for (int i = 0; i < 4; ++i) {
            v4f xv = *(const v4f*)&Xa[rg * 4 + i][k];
            acc[i][0] = __builtin_elementwise_fma(sp(xv.x), W0.xy, acc[i][0]);
            acc[i][1] = __builtin_elementwise_fma(sp(xv.x), W0.zw, acc[i][1]);
            acc[i][0] = __builtin_elementwise_fma(sp(xv.y), W1r.xy, acc[i][0]);
            acc[i][1] = __builtin_elementwise_fma(sp(xv.y), W1r.zw, acc[i][1]);
            acc[i][0] = __builtin_elementwise_fma(sp(xv.z), W2r.xy, acc[i][0]);
            acc[i][1] = __builtin_elementwise_fma(sp(xv.z), W2r.zw, acc[i][1]);
            acc[i][0] = __builtin_elementwise_fma(sp(xv.w), W3r.xy, acc[i][0]);
            acc[i][1] = __builtin_elementwise_fma(sp(xv.w), W3r.zw, acc[i][1]);
        }
    }
#pragma unroll
    for (int i = 0; i < 4; ++i) {
        int row = node0 + rg * 4 + i;
        if (row < N) {
            float4 o = make_float4(acc[i][0].x, acc[i][0].y, acc[i][1].x, acc[i][1].y);
            *(float4*)&out[(size_t)row * 128 + c] = o;
        }
    }
}

// ---------------------------------------------------------------- LN(128) + relu (f32 out)
__global__ __launch_bounds__(256)
void ln_relu_kernel(const float* __restrict__ x, const float* __restrict__ g,
                    const float* __restrict__ b, float* __restrict__ out, int N) {
    int lane = threadIdx.x & 63;
    int node = blockIdx.x * 4 + (threadIdx.x >> 6);
    if (node >= N) return;
    int c0 = lane * 2;
    float2 xv = *(const float2*)&x[(size_t)node * 128 + c0];
    float s = xv.x + xv.y;
    float q = xv.x * xv.x + xv.y * xv.y;
#pragma unroll
    for (int m = 1; m < 64; m <<= 1) { s += __shfl_xor(s, m, 64); q += __shfl_xor(q, m, 64); }
    float mu = s * (1.f / 128.f);
    float var = q * (1.f / 128.f) - mu * mu;
    float rs = rsqrtf(var + 1e-5f);
    float ox = fmaxf((xv.x - mu) * rs * g[c0] + b[c0], 0.f);
    float oy = fmaxf((xv.y - mu) * rs * g[c0 + 1] + b[c0 + 1], 0.f);
    float2 o; o.x = ox; o.y = oy;
    *(float2*)&out[(size_t)node * 128 + c0] = o;
}

// ---------------------------------------------------------------- LN(128) + relu (hi/lo bf16 out, for head)
__global__ __launch_bounds__(256)
void ln_relu_bf_kernel(const float* __restrict__ x, const float* __restrict__ g,
                       const float* __restrict__ b, unsigned short* __restrict__ outH,
                       unsigned short* __restrict__ outL, int N) {
    int lane = threadIdx.x & 63;
    int node = blockIdx.x * 4 + (threadIdx.x >> 6);
    if (node >= N) return;
    int c0 = lane * 2;
    float2 xv = *(const float2*)&x[(size_t)node * 128 + c0];
    float s = xv.x + xv.y;
    float q = xv.x * xv.x + xv.y * xv.y;
#pragma unroll
    for (int m = 1; m < 64; m <<= 1) { s += __shfl_xor(s, m, 64); q += __shfl_xor(q, m, 64); }
    float mu = s * (1.f / 128.f);
    float var = q * (1.f / 128.f) - mu * mu;
    float rs = rsqrtf(var + 1e-5f);
    float ox = fmaxf((xv.x - mu) * rs * g[c0] + b[c0], 0.f);
    float oy = fmaxf((xv.y - mu) * rs * g[c0 + 1] + b[c0 + 1], 0.f);
    unsigned short hx = f2bf(ox), hy = f2bf(oy);
    unsigned short lx = f2bf(ox - bf2f(hx)), ly = f2bf(oy - bf2f(hy));
    *(unsigned int*)&outH[(size_t)node * 128 + c0] = (unsigned int)hx | ((unsigned int)hy << 16);
    *(unsigned int*)&outL[(size_t)node * 128 + c0] = (unsigned int)lx | ((unsigned int)ly << 16);
}

// ---------------------------------------------------------------- GENConv aggregation (hi/lo bf16 output)
__global__ __launch_bounds__(256, 4)
void conv_kernel(const float* __restrict__ pre, const float* __restrict__ attr_perm,
                 const int* __restrict__ src_perm, const int* __restrict__ offs,
                 const float* __restrict__ edge_W, const float* __restrict__ edge_b,
                 const float* __restrict__ ts, int layer,
                 unsigned short* __restrict__ convH, unsigned short* __restrict__ convL, int N) {
    int lane = threadIdx.x & 63;
    int node = blockIdx.x * 4 + (threadIdx.x >> 6);
    if (node >= N) return;
    int c0 = lane * 2;
    v2f wE[16];
#pragma unroll
    for (int k = 0; k < 16; ++k) {
        wE[k].x = edge_W[k * 128 + c0];
        wE[k].y = edge_W[k * 128 + c0 + 1];
    }
    v2f eb; eb.x = edge_b[c0]; eb.y = edge_b[c0 + 1];
    float t = ts[layer];
    int i0 = offs[node], i1 = offs[node + 1];
    v2f xself = *(const v2f*)&pre[(size_t)node * 128 + c0];
    float sx = 0.f, sy = 0.f, wx = 0.f, wy = 0.f;
    int i = i0;
    for (; i + 1 < i1; i += 2) {
        int iu = __builtin_amdgcn_readfirstlane(i);
        int sa = src_perm[iu];
        int sb = src_perm[iu + 1];
        const v4f* ar = (const v4f*)(attr_perm + (size_t)iu * 16);
        v4f A0 = ar[0], A1 = ar[1], A2 = ar[2], A3 = ar[3];
        v4f B0 = ar[4], B1 = ar[5], B2 = ar[6], B3 = ar[7];
        v2f xa = *(const v2f*)&pre[(size_t)sa * 128 + c0];
        v2f xb = *(const v2f*)&pre[(size_t)sb * 128 + c0];
        v2f ea = eb, eb2 = eb;
        ea  = __builtin_elementwise_fma(sp(A0.x), wE[0], ea);
        eb2 = __builtin_elementwise_fma(sp(B0.x), wE[0], eb2);
        ea  = __builtin_elementwise_fma(sp(A0.y), wE[1], ea);
        eb2 = __builtin_elementwise_fma(sp(B0.y), wE[1], eb2);
        ea  = __builtin_elementwise_fma(sp(A0.z), wE[2], ea);
        eb2 = __builtin_elementwise_fma(sp(B0.z), wE[2], eb2);
        ea  = __builtin_elementwise_fma(sp(A0.w), wE[3], ea);
        eb2 = __builtin_elementwise_fma(sp(B0.w), wE[3], eb2);
        ea  = __builtin_elementwise_fma(sp(A1.x), wE[4], ea);
        eb2 = __builtin_elementwise_fma(sp(B1.x), wE[4], eb2);
        ea  = __builtin_elementwise_fma(sp(A1.y), wE[5], ea);
        eb2 = __builtin_elementwise_fma(sp(B1.y), wE[5], eb2);
        ea  = __builtin_elementwise_fma(sp(A1.z), wE[6], ea);
        eb2 = __builtin_elementwise_fma(sp(B1.z), wE[6], eb2);
        ea  = __builtin_elementwise_fma(sp(A1.w), wE[7], ea);
        eb2 = __builtin_elementwise_fma(sp(B1.w), wE[7], eb2);
        ea  = __builtin_elementwise_fma(sp(A2.x), wE[8], ea);
        eb2 = __builtin_elementwise_fma(sp(B2.x), wE[8], eb2);
        ea  = __builtin_elementwise_fma(sp(A2.y), wE[9], ea);
        eb2 = __builtin_elementwise_fma(sp(B2.y), wE[9], eb2);
        ea  = __builtin_elementwise_fma(sp(A2.z), wE[10], ea);
        eb2 = __builtin_elementwise_fma(sp(B2.z), wE[10], eb2);
        ea  = __builtin_elementwise_fma(sp(A2.w), wE[11], ea);
        eb2 = __builtin_elementwise_fma(sp(B2.w), wE[11], eb2);
        ea  = __builtin_elementwise_fma(sp(A3.x), wE[12], ea);
        eb2 = __builtin_elementwise_fma(sp(B3.x), wE[12], eb2);
        ea  = __builtin_elementwise_fma(sp(A3.y), wE[13], ea);
        eb2 = __builtin_elementwise_fma(sp(B3.y), wE[13], eb2);
        ea  = __builtin_elementwise_fma(sp(A3.z), wE[14], ea);
        eb2 = __builtin_elementwise_fma(sp(B3.z), wE[14], eb2);
        ea  = __builtin_elementwise_fma(sp(A3.w), wE[15], ea);
        eb2 = __builtin_elementwise_fma(sp(B3.w), wE[15], eb2);
        float mgax = fmaxf(xa.x + ea.x, 0.f) + EPS_MSG;
        float mgay = fmaxf(xa.y + ea.y, 0.f) + EPS_MSG;
        float mgbx = fmaxf(xb.x + eb2.x, 0.f) + EPS_MSG;
        float mgby = fmaxf(xb.y + eb2.y, 0.f) + EPS_MSG;
        float exa = __expf(mgax * t), eya = __expf(mgay * t);
        float exb = __expf(mgbx * t), eyb = __expf(mgby * t);
        sx += exa + exb; sy += eya + eyb;
        wx = fmaf(exa, mgax, wx); wx = fmaf(exb, mgbx, wx);
        wy = fmaf(eya, mgay, wy); wy = fmaf(eyb, mgby, wy);
    }
    if (i < i1) {
        int iu = __builtin_amdgcn_readfirstlane(i);
        int sn = src_perm[iu];
        const v4f* ar = (const v4f*)(attr_perm + (size_t)iu * 16);
        v4f A0 = ar[0], A1 = ar[1], A2 = ar[2], A3 = ar[3];
        v2f xv = *(const v2f*)&pre[(size_t)sn * 128 + c0];
        v2f ea = eb;
        ea = __builtin_elementwise_fma(sp(A0.x), wE[0], ea);
        ea = __builtin_elementwise_fma(sp(A0.y), wE[1], ea);
        ea = __builtin_elementwise_fma(sp(A0.z), wE[2], ea);
        ea = __builtin_elementwise_fma(sp(A0.w), wE[3], ea);
        ea = __builtin_elementwise_fma(sp(A1.x), wE[4], ea);
        ea = __builtin_elementwise_fma(sp(A1.y), wE[5], ea);
        ea = __builtin_elementwise_fma(sp(A1.z), wE[6], ea);
        ea = __builtin_elementwise_fma(sp(A1.w), wE[7], ea);
        ea = __builtin_elementwise_fma(sp(A2.x), wE[8], ea);
        ea = __builtin_elementwise_fma(sp(A2.y), wE[9], ea);
        ea = __builtin_elementwise_fma(sp(A2.z), wE[10], ea);
        ea = __builtin_elementwise_fma(sp(A2.w), wE[11], ea);
        ea = __builtin_elementwise_fma(sp(A3.x), wE[12], ea);
        ea = __builtin_elementwise_fma(sp(A3.y), wE[13], ea);
        ea = __builtin_elementwise_fma(sp(A3.z), wE[14], ea);
        ea = __builtin_elementwise_fma(sp(A3.w), wE[15], ea);
        float mgx = fmaxf(xv.x + ea.x, 0.f) + EPS_MSG;
        float mgy = fmaxf(xv.y + ea.y, 0.f) + EPS_MSG;
        float ex = __expf(mgx * t), ey = __expf(mgy * t);
        sx += ex; sy += ey;
        wx = fmaf(ex, mgx, wx);
        wy = fmaf(ey, mgy, wy);
    }
    float ax = (sx > 0.f) ? wx / sx : 0.f;
    float ay = (sy > 0.f) ? wy / sy : 0.f;
    float ox = ax + xself.x;
    float oy = ay + xself.y;
    unsigned short hx = f2bf(ox), hy = f2bf(oy);
    unsigned short lx = f2bf(ox - bf2f(hx)), ly = f2bf(oy - bf2f(hy));
    *(unsigned int*)&convH[(size_t)node * 128 + c0] = (unsigned int)hx | ((unsigned int)hy << 16);
    *(unsigned int*)&convL[(size_t)node * 128 + c0] = (unsigned int)lx | ((unsigned int)ly << 16);
}

// ---------------------------------------------------------------- fused MLP via MFMA (split hi/lo bf16)
template <int RES>
__global__ __launch_bounds__(256)
void mlp_mfma(const unsigned short* __restrict__ convH, const unsigned short* __restrict__ convL,
              const unsigned short* __restrict__ W1H, const unsigned short* __restrict__ W1L,
              const float* __restrict__ b1, const float* __restrict__ g1, const float* __restrict__ be1,
              const unsigned short* __restrict__ W2H, const unsigned short* __restrict__ W2L,
              const float* __restrict__ b2, const float* __restrict__ xold,
              float* __restrict__ xnew, int N) {
    __shared__ __align__(16) unsigned short XaH[32][136];
    __shared__ __align__(16) unsigned short XaL[32][136];
    __shared__ __align__(16) unsigned short XhH[32][264];
    __shared__ __align__(16) unsigned short XhL[32][264];
    __shared__ float2 ps[4][32];
    int tid = threadIdx.x;
    int w = tid >> 6;
    int lane = tid & 63;
    int g = lane >> 4;
    int r = lane & 15;
    int node0 = blockIdx.x * 32;
    {
        int row = tid >> 3;
        int cb = (tid & 7) * 16;
        uint4 h0 = make_uint4(0, 0, 0, 0), h1 = h0, l0 = h0, l1 = h0;
        if (node0 + row < N) {
            const uint4* pH = (const uint4*)&convH[(size_t)(node0 + row) * 128 + cb];
            const uint4* pL = (const uint4*)&convL[(size_t)(node0 + row) * 128 + cb];
            h0 = pH[0]; h1 = pH[1];
            l0 = pL[0]; l1 = pL[1];
        }
        *(uint4*)&XaH[row][cb] = h0; *(uint4*)&XaH[row][cb + 8] = h1;
        *(uint4*)&XaL[row][cb] = l0; *(uint4*)&XaL[row][cb + 8] = l1;
    }
    __syncthreads();
    f32x4 acc1[2][4];
#pragma unroll
    for (int cf = 0; cf < 4; ++cf) {
        float bv = b1[(w * 4 + cf) * 16 + r];
        f32x4 iv; iv[0] = bv; iv[1] = bv; iv[2] = bv; iv[3] = bv;
        acc1[0][cf] = iv; acc1[1][cf] = iv;
    }
#pragma unroll
    for (int kstep = 0; kstep < 4; ++kstep) {
        int ko = kstep * 32 + g * 8;
        bf16x8 aH0 = *(const bf16x8*)&XaH[r][ko];
        bf16x8 aH1 = *(const bf16x8*)&XaH[16 + r][ko];
        bf16x8 aL0 = *(const bf16x8*)&XaL[r][ko];
        bf16x8 aL1 = *(const bf16x8*)&XaL[16 + r][ko];
#pragma unroll
        for (int cf = 0; cf < 4; ++cf) {
            int c16 = w * 4 + cf;
            bf16x8 bH = *(const bf16x8*)&W1H[(((size_t)c16 * 4 + kstep) * 64 + lane) * 8];
            bf16x8 bL = *(const bf16x8*)&W1L[(((size_t)c16 * 4 + kstep) * 64 + lane) * 8];
            acc1[0][cf] = __builtin_amdgcn_mfma_f32_16x16x32_bf16(aH0, bH, acc1[0][cf], 0, 0, 0);
            acc1[0][cf] = __builtin_amdgcn_mfma_f32_16x16x32_bf16(aH0, bL, acc1[0][cf], 0, 0, 0);
            acc1[0][cf] = __builtin_amdgcn_mfma_f32_16x16x32_bf16(aL0, bH, acc1[0][cf], 0, 0, 0);
            acc1[1][cf] = __builtin_amdgcn_mfma_f32_16x16x32_bf16(aH1, bH, acc1[1][cf], 0, 0, 0);
            acc1[1][cf] = __builtin_amdgcn_mfma_f32_16x16x32_bf16(aH1, bL, acc1[1][cf], 0, 0, 0);
            acc1[1][cf] = __builtin_amdgcn_mfma_f32_16x16x32_bf16(aL1, bH, acc1[1][cf], 0, 0, 0);
        }
    }
    {
        float s_[2][4], q_[2][4];
#pragma unroll
        for (int rf = 0; rf < 2; ++rf)
#pragma unroll
            for (int reg = 0; reg < 4; ++reg) {
                float s = 0.f, q = 0.f;
#pragma unroll
                for (int cf = 0; cf < 4; ++cf) {
                    float v = acc1[rf][cf][reg];
                    s += v; q += v * v;
                }
                s_[rf][reg] = s; q_[rf][reg] = q;
            }
#pragma unroll
        for (int m = 1; m < 16; m <<= 1) {
#pragma unroll
            for (int rf = 0; rf < 2; ++rf)
#pragma unroll
                for (int reg = 0; reg < 4; ++reg) {
                    s_[rf][reg] += __shfl_xor(s_[rf][reg], m, 64);
                    q_[rf][reg] += __shfl_xor(q_[rf][reg], m, 64);
                }
        }
        if (r == 0) {
#pragma unroll
            for (int rf = 0; rf < 2; ++rf)
#pragma unroll
                for (int reg = 0; reg < 4; ++reg)
                    ps[w][rf * 16 + g * 4 + reg] = make_float2(s_[rf][reg], q_[rf][reg]);
        }
    }
    __syncthreads();
    {
        float gv[4], bev[4];
#pragma unroll
        for (int cf = 0; cf < 4; ++cf) {
            gv[cf] = g1[(w * 4 + cf) * 16 + r];
            bev[cf] = be1[(w * 4 + cf) * 16 + r];
        }
#pragma unroll
        for (int rf = 0; rf < 2; ++rf)
#pragma unroll
            for (int reg = 0; reg < 4; ++reg) {
                int row = rf * 16 + g * 4 + reg;
                float2 t0 = ps[0][row], t1 = ps[1][row], t2 = ps[2][row], t3 = ps[3][row];
                float s = t0.x + t1.x + t2.x + t3.x;
                float q = t0.y + t1.y + t2.y + t3.y;
                float mu = s * (1.f / 256.f);
                float var = q * (1.f / 256.f) - mu * mu;
                float rs = rsqrtf(var + 1e-5f);
#pragma unroll
                for (int cf = 0; cf < 4; ++cf) {
                    float h = fmaxf((acc1[rf][cf][reg] - mu) * rs * gv[cf] + bev[cf], 0.f);
                    unsigned short hh = f2bf(h);
                    unsigned short hl = f2bf(h - bf2f(hh));
                    int col = (w * 4 + cf) * 16 + r;
                    XhH[row][col] = hh;
                    XhL[row][col] = hl;
                }
            }
    }
    __syncthreads();
    f32x4 acc2[2][2];
#pragma unroll
    for (int cf = 0; cf < 2; ++cf) {
        float bv = b2[(w * 2 + cf) * 16 + r];
        f32x4 iv; iv[0] = bv; iv[1] = bv; iv[2] = bv; iv[3] = bv;
        acc2[0][cf] = iv; acc2[1][cf] = iv;
    }
#pragma unroll
    for (int kstep = 0; kstep < 8; ++kstep) {
        int ko = kstep * 32 + g * 8;
        bf16x8 aH0 = *(const bf16x8*)&XhH[r][ko];
        bf16x8 aH1 = *(const bf16x8*)&XhH[16 + r][ko];
        bf16x8 aL0 = *(const bf16x8*)&XhL[r][ko];
        bf16x8 aL1 = *(const bf16x8*)&XhL[16 + r][ko];
#pragma unroll
        for (int cf = 0; cf < 2; ++cf) {
            int c16 = w * 2 + cf;
            bf16x8 bH = *(const bf16x8*)&W2H[(((size_t)c16 * 8 + kstep) * 64 + lane) * 8];
            bf16x8 bL = *(const bf16x8*)&W2L[(((size_t)c16 * 8 + kstep) * 64 + lane) * 8];
            acc2[0][cf] = __builtin_amdgcn_mfma_f32_16x16x32_bf16(aH0, bH, acc2[0][cf], 0, 0, 0);
            acc2[0][cf] = __builtin_amdgcn_mfma_f32_16x16x32_bf16(aH0, bL, acc2[0][cf], 0, 0, 0);
            acc2[0][cf] = __builtin_amdgcn_mfma_f32_16x16x32_bf16(aL0, bH, acc2[0][cf], 0, 0, 0);
            acc2[1][cf] = __builtin_amdgcn_mfma_f32_16x16x32_bf16(aH1, bH, acc2[1][cf], 0, 0, 0);
            acc2[1][cf] = __builtin_amdgcn_mfma_f32_16x16x32_bf16(aH1, bL, acc2[1][cf], 0, 0, 0);
            acc2[1][cf] = __builtin_amdgcn_mfma_f32_16x16x32_bf16(aL1, bH, acc2[1][cf], 0, 0, 0);
        }
    }
#pragma unroll
    for (int rf = 0; rf < 2; ++rf)
#pragma unroll
        for (int reg = 0; reg < 4; ++reg) {
            int row = node0 + rf * 16 + g * 4 + reg;
            if (row < N) {
#pragma unroll
                for (int cf = 0; cf < 2; ++cf) {
                    int col = (w * 2 + cf) * 16 + r;
                    float v = acc2[rf][cf][reg];
                    if (RES) v += xold[(size_t)row * 128 + col];
                    xnew[(size_t)row * 128 + col] = v;
                }
            }
        }
}

// ---------------------------------------------------------------- head via MFMA
// out[n] = relu(pre[n]@W0[:128] + gf0*W0[128] + gf1*W0[129] + b0) @ W1h + b1h
__global__ __launch_bounds__(256)
void head_mfma(const unsigned short* __restrict__ PREH, const unsigned short* __restrict__ PREL,
               const unsigned short* __restrict__ W0H, const unsigned short* __restrict__ W0L,
               const float* __restrict__ W0, const float* __restrict__ b0,
               const float* __restrict__ gf, const float* __restrict__ W1h,
               const float* __restrict__ b1h, float* __restrict__ out, int N) {
    __shared__ __align__(16) unsigned short XH[32][136];
    __shared__ __align__(16) unsigned short XL[32][136];
    __shared__ float gf0s[32], gf1s[32];
    __shared__ float psum[4][32];
    int tid = threadIdx.x;
    int w = tid >> 6;
    int lane = tid & 63;
    int g = lane >> 4;
    int r = lane & 15;
    int node0 = blockIdx.x * 32;
    {
        int row = tid >> 3;
        int cb = (tid & 7) * 16;
        uint4 h0 = make_uint4(0, 0, 0, 0), h1 = h0, l0 = h0, l1 = h0;
        if (node0 + row < N) {
            const uint4* pH = (const uint4*)&PREH[(size_t)(node0 + row) * 128 + cb];
            const uint4* pL = (const uint4*)&PREL[(size_t)(node0 + row) * 128 + cb];
            h0 = pH[0]; h1 = pH[1];
            l0 = pL[0]; l1 = pL[1];
        }
        *(uint4*)&XH[row][cb] = h0; *(uint4*)&XH[row][cb + 8] = h1;
        *(uint4*)&XL[row][cb] = l0; *(uint4*)&XL[row][cb + 8] = l1;
        if (tid < 32) {
            int node = node0 + tid;
            float f0 = 0.f, f1 = 0.f;
            if (node < N) {
                int a = node / 1000;
                int i0 = 2 * a, i1 = 2 * a + 1;
                f0 = (i0 < 50) ? gf[i0 * 2] : gf[(i0 - 50) * 2 + 1];
                f1 = (i1 < 50) ? gf[i1 * 2] : gf[(i1 - 50) * 2 + 1];
            }
            gf0s[tid] = f0;
            gf1s[tid] = f1;
        }
    }
    __syncthreads();
    f32x4 acc[2][2];
#pragma unroll
    for (int cf = 0; cf < 2; ++cf) {
        float bv = b0[(w * 2 + cf) * 16 + r];
        f32x4 iv; iv[0] = bv; iv[1] = bv; iv[2] = bv; iv[3] = bv;
        acc[0][cf] = iv; acc[1][cf] = iv;
    }
#pragma unroll
    for (int kstep = 0; kstep < 4; ++kstep) {
        int ko = kstep * 32 + g * 8;
        bf16x8 aH0 = *(const bf16x8*)&XH[r][ko];
        bf16x8 aH1 = *(const bf16x8*)&XH[16 + r][ko];
        bf16x8 aL0 = *(const bf16x8*)&XL[r][ko];
        bf16x8 aL1 = *(const bf16x8*)&XL[16 + r][ko];
#pragma unroll
        for (int cf = 0; cf < 2; ++cf) {
            int c16 = w * 2 + cf;
            bf16x8 bH = *(const bf16x8*)&W0H[(((size_t)c16 * 4 + kstep) * 64 + lane) * 8];
            bf16x8 bL = *(const bf16x8*)&W0L[(((size_t)c16 * 4 + kstep) * 64 + lane) * 8];
            acc[0][cf] = __builtin_amdgcn_mfma_f32_16x16x32_bf16(aH0, bH, acc[0][cf], 0, 0, 0);
            acc[0][cf] = __builtin_amdgcn_mfma_f32_16x16x32_bf16(aH0, bL, acc[0][cf], 0, 0, 0);
            acc[0][cf] = __builtin_amdgcn_mfma_f32_16x16x32_bf16(aL0, bH, acc[0][cf], 0, 0, 0);
            acc[1][cf] = __builtin_amdgcn_mfma_f32_16x16x32_bf16(aH1, bH, acc[1][cf], 0, 0, 0);
            acc[1][cf] = __builtin_amdgcn_mfma_f32_16x16x32_bf16(aH1, bL, acc[1][cf], 0, 0, 0);
            acc[1][cf] = __builtin_amdgcn_mfma_f32_16x16x32_bf16(aL1, bH, acc[1][cf], 0, 0, 0);
        }
    }
    // epilogue: + graph-feature rows, relu, dot with W1h, reduce over cols
    {
        float w1v[2], wg0[2], wg1[2];
#pragma unroll
        for (int cf = 0; cf < 2; ++cf) {
            int col = (w * 2 + cf) * 16 + r;
            w1v[cf] = W1h[col];
            wg0[cf] = W0[128 * 128 + col];
            wg1[cf] = W0[129 * 128 + col];
        }
#pragma unroll
        for (int rf = 0; rf < 2; ++rf)
#pragma unroll
            for (int reg = 0; reg < 4; ++reg) {
                int rowl = rf * 16 + g * 4 + reg;
                float f0 = gf0s[rowl], f1 = gf1s[rowl];
                float p = 0.f;
#pragma unroll
                for (int cf = 0; cf < 2; ++cf) {
                    float v = acc[rf][cf][reg] + f0 * wg0[cf] + f1 * wg1[cf];
                    v = fmaxf(v, 0.f);
                    p = fmaf(v, w1v[cf], p);
                }
#pragma unroll
                for (int m = 1; m < 16; m <<= 1) p += __shfl_xor(p, m, 64);
                if (r == 0) psum[w][rowl] = p;
            }
    }
    __syncthreads();
    if (tid < 32) {
        int node = node0 + tid;
        if (node < N) {
            float s = psum[0][tid] + psum[1][tid] + psum[2][tid] + psum[3][tid] + b1h[0];
            out[node] = s;
        }
    }
}

// ---------------------------------------------------------------- launch
extern "C" void kernel_launch(void* const* d_in, const int* in_sizes, int n_in,
                              void* d_out, int out_size, void* d_ws, size_t ws_size,
                              hipStream_t stream) {
    const float* x_in    = (const float*)d_in[0];
    const int*   ei      = (const int*)d_in[1];
    const float* edge_attr = (const float*)d_in[2];
    const float* gf      = (const float*)d_in[3];
    const float* node_W  = (const float*)d_in[4];
    const float* node_b  = (const float*)d_in[5];
    const float* edge_W  = (const float*)d_in[6];
    const float* edge_b  = (const float*)d_in[7];
    const float* ts      = (const float*)d_in[8];
    const float* W1s     = (const float*)d_in[9];
    const float* b1s     = (const float*)d_in[10];
    const float* g1s     = (const float*)d_in[11];
    const float* be1s    = (const float*)d_in[12];
    const float* W2s     = (const float*)d_in[13];
    const float* b2s     = (const float*)d_in[14];
    const float* ln_gs   = (const float*)d_in[15];
    const float* ln_bs   = (const float*)d_in[16];
    const float* hW0     = (const float*)d_in[17];
    const float* hb0     = (const float*)d_in[18];
    const float* hW1     = (const float*)d_in[19];
    const float* hb1     = (const float*)d_in[20];

    const int N = in_sizes[0] / 64;
    const int E = in_sizes[1] / 2;
    const int NB = (N + 1023) / 1024;

    char* ws = (char*)d_ws;
    size_t off = 0;
    auto alloc = [&](size_t bytes) -> void* {
        void* p = ws + off;
        off = (off + bytes + 255) & ~(size_t)255;
        return p;
    };
    float* X     = (float*)alloc((size_t)N * 128 * 4);
    float* PRE   = (float*)alloc((size_t)N * 128 * 4);
    unsigned short* CONVH = (unsigned short*)alloc((size_t)N * 128 * 2);
    unsigned short* CONVL = (unsigned short*)alloc((size_t)N * 128 * 2);
    unsigned short* W1H = (unsigned short*)alloc((size_t)4 * 128 * 256 * 2);
    unsigned short* W1L = (unsigned short*)alloc((size_t)4 * 128 * 256 * 2);
    unsigned short* W2H = (unsigned short*)alloc((size_t)4 * 256 * 128 * 2);
    unsigned short* W2L = (unsigned short*)alloc((size_t)4 * 256 * 128 * 2);
    int* SRCP    = (int*)alloc((size_t)E * 4);
    int* DEG     = (int*)alloc((size_t)N * 4);
    int* FILL    = (int*)alloc((size_t)N * 4);
    int* OFFS    = (int*)alloc((size_t)(N + 1) * 4);
    int* BSUM    = (int*)alloc((size_t)(NB + 1) * 4);
    float* ATTRP = (float*)alloc((size_t)E * 16 * 4);

    // W0 head fragments overlay the DEG buffer (DEG dead after scan1; 64 KB < N*4)
    unsigned short* W0H = (unsigned short*)DEG;
    unsigned short* W0L = W0H + 128 * 128;

    // weight swizzle (once per call)
    const int TOT = 4 * 128 * 256;
    wswz_kernel<<<(TOT + 255) / 256, 256, 0, stream>>>(W1s, W1H, W1L, 128, 256, TOT);
    wswz_kernel<<<(TOT + 255) / 256, 256, 0, stream>>>(W2s, W2H, W2L, 256, 128, TOT);

    // CSR build
    zero2_kernel<<<(N + 255) / 256, 256, 0, stream>>>(DEG, FILL, N);
    deg_kernel<<<(E + 255) / 256, 256, 0, stream>>>(ei, DEG, E);
    scan1_kernel<<<NB, 1024, 0, stream>>>(DEG, OFFS, BSUM, N);
    scan2_kernel<<<1, 64, 0, stream>>>(BSUM, NB);
    scan3_kernel<<<(N + 256) / 256, 256, 0, stream>>>(OFFS, BSUM, N);
    scatter_kernel<<<(E + 255) / 256, 256, 0, stream>>>(ei, edge_attr, OFFS, FILL, SRCP, ATTRP, E);
    // DEG is dead now -> swizzle head W0 into its storage
    wswz_kernel<<<(128 * 128 + 255) / 256, 256, 0, stream>>>(hW0, W0H, W0L, 128, 128, 128 * 128);

    encode_kernel<<<(N + 31) / 32, 256, 0, stream>>>(x_in, node_W, node_b, X, N);

    for (int layer = 0; layer < 4; ++layer) {
        const float* pre = X;
        if (layer > 0) {
            ln_relu_kernel<<<(N + 3) / 4, 256, 0, stream>>>(X, ln_gs + 128 * layer, ln_bs + 128 * layer, PRE, N);
            pre = PRE;
        }
        conv_kernel<<<(N + 3) / 4, 256, 0, stream>>>(pre, ATTRP, SRCP, OFFS, edge_W, edge_b,
                                                     ts, layer, CONVH, CONVL, N);
        const unsigned short* w1h = W1H + (size_t)layer * 128 * 256;
        const unsigned short* w1l = W1L + (size_t)layer * 128 * 256;
        const unsigned short* w2h = W2H + (size_t)layer * 256 * 128;
        const unsigned short* w2l = W2L + (size_t)layer * 256 * 128;
        if (layer == 0)
            mlp_mfma<0><<<(N + 31) / 32, 256, 0, stream>>>(CONVH, CONVL, w1h, w1l,
                                                           b1s + layer * 256, g1s + layer * 256, be1s + layer * 256,
                                                           w2h, w2l, b2s + layer * 128, X, X, N);
        else
            mlp_mfma<1><<<(N + 31) / 32, 256, 0, stream>>>(CONVH, CONVL, w1h, w1l,
                                                           b1s + layer * 256, g1s + layer * 256, be1s + layer * 256,
                                                           w2h, w2l, b2s + layer * 128, X, X, N);
    }

    // final LN -> hi/lo bf16 into the (now free) CONVH/CONVL, then MFMA head
    ln_relu_bf_kernel<<<(N + 3) / 4, 256, 0, stream>>>(X, ln_gs, ln_bs, CONVH, CONVL, N);
    head_mfma<<<(N + 31) / 32, 256, 0, stream>>>(CONVH, CONVL, W0H, W0L, hW0, hb0, gf, hW1, hb1,
                                                 (float*)d_out, N);
}